// Round 2
// baseline (812.282 us; speedup 1.0000x reference)
//
#include <hip/hip_runtime.h>
#include <hip/hip_bf16.h>
#include <math.h>

#define NN 10000
#define EE 80000
#define SDIM 18
#define HID 1024
#define NLAYERS 4
#define GHID 256

typedef __bf16 bf16;
typedef __bf16 bf16x8 __attribute__((ext_vector_type(8)));
typedef __bf16 bf16x4 __attribute__((ext_vector_type(4)));
typedef float f32x4 __attribute__((ext_vector_type(4)));

#define AS1C(p) ((const __attribute__((address_space(1))) void*)(p))
#define AS3(p)  ((__attribute__((address_space(3))) void*)(p))

// ---------------- CSR build: count ----------------
__global__ void count_kernel(const int* __restrict__ ei, int* __restrict__ cnt) {
    int e = blockIdx.x * 256 + threadIdx.x;
    if (e < EE) atomicAdd(&cnt[ei[EE + e]], 1);
}

// ---------------- CSR build: exclusive scan (single block) ----------------
__global__ __launch_bounds__(256) void scan_kernel(const int* __restrict__ cnt,
                                                   int* __restrict__ offs,
                                                   int* __restrict__ cursor,
                                                   float* __restrict__ degF) {
    const int CH = 40;  // 256*40 = 10240 >= NN
    __shared__ int partial[256];
    int t = threadIdx.x;
    int base = t * CH;
    int local[CH];
    int sum = 0;
#pragma unroll
    for (int i = 0; i < CH; ++i) {
        int idx = base + i;
        int v = (idx < NN) ? cnt[idx] : 0;
        local[i] = sum;
        sum += v;
    }
    partial[t] = sum;
    __syncthreads();
    for (int off = 1; off < 256; off <<= 1) {
        int v = (t >= off) ? partial[t - off] : 0;
        __syncthreads();
        partial[t] += v;
        __syncthreads();
    }
    int excl = (t == 0) ? 0 : partial[t - 1];
#pragma unroll
    for (int i = 0; i < CH; ++i) {
        int idx = base + i;
        if (idx < NN) {
            int o = excl + local[i];
            offs[idx] = o;
            cursor[idx] = o;
            degF[idx] = (float)cnt[idx];
        }
    }
    if (t == 255) offs[NN] = partial[255];
}

// ---------------- CSR build: scatter edge sources ----------------
__global__ void scatter_kernel(const int* __restrict__ ei, int* __restrict__ cursor,
                               int* __restrict__ esrc) {
    int e = blockIdx.x * 256 + threadIdx.x;
    if (e < EE) {
        int dst = ei[EE + e];
        int pos = atomicAdd(&cursor[dst], 1);
        esrc[pos] = ei[e];
    }
}

// ---------------- fused prep: all weight transposes + swt + cb + cnt-zero ----------------
__global__ __launch_bounds__(256) void prep_kernel(const float* __restrict__ W1,
                                                   const float* __restrict__ W2,
                                                   const float* __restrict__ gw1,
                                                   const float* __restrict__ sw,
                                                   const float* __restrict__ b1,
                                                   bf16* __restrict__ WT,
                                                   bf16* __restrict__ W2t,
                                                   bf16* __restrict__ gw1t,
                                                   bf16* __restrict__ swt,
                                                   float* __restrict__ cb,
                                                   int* __restrict__ cnt) {
    __shared__ float td[32][33];
    __shared__ float tb[32][33];
    const size_t H2 = (size_t)HID * HID;
    int b = blockIdx.x;
    int tx = threadIdx.x & 31, ty = threadIdx.x >> 5;  // (32,8)

    if (b < 4096) {  // W1 fused diff transpose
        int l = b >> 10, r = b & 1023;
        int bx = (r & 31) * 32, by = (r >> 5) * 32;
        const float* s = W1 + (size_t)l * 2 * H2;
        bf16* d = WT + (size_t)l * 2 * H2;
#pragma unroll
        for (int r4 = 0; r4 < 4; ++r4) {
            int row = by + ty + r4 * 8;
            float vt = s[(size_t)row * HID + bx + tx];
            float vb = s[H2 + (size_t)row * HID + bx + tx];
            td[ty + r4 * 8][tx] = vt - vb;
            tb[ty + r4 * 8][tx] = vb;
        }
        __syncthreads();
#pragma unroll
        for (int r4 = 0; r4 < 4; ++r4) {
            int orow = bx + ty + r4 * 8;
            d[(size_t)orow * HID + by + tx] = (bf16)td[tx][ty + r4 * 8];
            d[(size_t)(HID + orow) * HID + by + tx] = (bf16)tb[tx][ty + r4 * 8];
        }
    } else if (b < 8192) {  // W2 transpose
        int sub = b - 4096;
        int l = sub >> 10, r = sub & 1023;
        int bx = (r & 31) * 32, by = (r >> 5) * 32;
        const float* s = W2 + (size_t)l * H2;
        bf16* d = W2t + (size_t)l * H2;
#pragma unroll
        for (int r4 = 0; r4 < 4; ++r4) {
            int row = by + ty + r4 * 8;
            td[ty + r4 * 8][tx] = s[(size_t)row * HID + bx + tx];
        }
        __syncthreads();
#pragma unroll
        for (int r4 = 0; r4 < 4; ++r4) {
            int orow = bx + ty + r4 * 8;
            d[(size_t)orow * HID + by + tx] = (bf16)td[tx][ty + r4 * 8];
        }
    } else if (b < 8448) {  // gw1 [1024][256] -> gw1t [256][1024]
        int sub = b - 8192;
        int bx = (sub & 7) * 32, by = (sub >> 3) * 32;
#pragma unroll
        for (int r4 = 0; r4 < 4; ++r4) {
            int row = by + ty + r4 * 8;
            td[ty + r4 * 8][tx] = gw1[(size_t)row * GHID + bx + tx];
        }
        __syncthreads();
#pragma unroll
        for (int r4 = 0; r4 < 4; ++r4) {
            int orow = bx + ty + r4 * 8;
            gw1t[(size_t)orow * HID + by + tx] = (bf16)td[tx][ty + r4 * 8];
        }
    } else if (b < 8576) {  // swt[32][1024] = sw[1024][18]^T zero-padded
        int i = (b - 8448) * 256 + threadIdx.x;
        int n = i >> 10, k = i & 1023;
        swt[i] = (bf16)(n < SDIM ? sw[k * SDIM + n] : 0.f);
    } else if (b < 8608) {  // cb[l][2048] = [b1[l] ; 0]
        int i = (b - 8576) * 256 + threadIdx.x;
        int l = i >> 11, c = i & 2047;
        cb[i] = (c < HID) ? b1[l * HID + c] : 0.f;
    } else {  // cnt zero
        int i = (b - 8608) * 256 + threadIdx.x;
        if (i < NN) cnt[i] = 0;
    }
}

// ---------------- h0 = sin(x@pw)*cos(x@pw) -> bf16 ----------------
__global__ __launch_bounds__(256) void proj_kernel(const float* __restrict__ x,
                                                   const float* __restrict__ pw,
                                                   bf16* __restrict__ hb) {
    int row = blockIdx.y;
    int col = blockIdx.x * 256 + threadIdx.x;
    __shared__ float xr[SDIM];
    if (threadIdx.x < SDIM) xr[threadIdx.x] = x[row * SDIM + threadIdx.x];
    __syncthreads();
    float acc = 0.f;
#pragma unroll
    for (int k = 0; k < SDIM; ++k) acc += xr[k] * pw[k * HID + col];
    hb[(size_t)row * HID + col] = (bf16)(sinf(acc) * cosf(acc));
}

// ---------------- old 128x128 MFMA GEMM (kept for ghost head, N=256) ----------------
template <int RELU, int HAS_BIAS, int HAS_RS, int WF32, int WB16>
__global__ __launch_bounds__(256) void mgemm_kernel(const bf16* __restrict__ A,
                                                    const bf16* __restrict__ Bt,
                                                    float* __restrict__ C,
                                                    bf16* __restrict__ Cb,
                                                    const float* __restrict__ bias,
                                                    const float* __restrict__ rowscale,
                                                    int M, int N, int K) {
    __shared__ bf16 As[2][128 * 32];
    __shared__ bf16 Bs[2][128 * 32];
    const int tid = threadIdx.x;

    const int num_n = gridDim.x, num_m = gridDim.y;
    int bid = blockIdx.x + blockIdx.y * num_n;
    const int GROUP = 8;
    int width = GROUP * num_n;
    int group = bid / width;
    int rem = bid - group * width;
    int rows_ing = num_m - group * GROUP;
    rows_ing = rows_ing < GROUP ? rows_ing : GROUP;
    int by = group * GROUP + rem % rows_ing;
    int bx = rem / rows_ing;
    const int m0 = by * 128;
    const int n0 = bx * 128;

    const int wave = tid >> 6;
    const int wr = (wave >> 1) * 64, wc = (wave & 1) * 64;
    const int lane = tid & 63;
    const int quad = lane >> 4, r15 = lane & 15;

    f32x4 acc[4][4] = {};

    const int s0 = tid, s1 = 256 + tid;
    int ar0 = m0 + (s0 >> 2); ar0 = ar0 < M ? ar0 : M - 1;
    int ar1 = m0 + (s1 >> 2); ar1 = ar1 < M ? ar1 : M - 1;
    const bf16* ga0 = A + (size_t)ar0 * K + (s0 & 3) * 8;
    const bf16* ga1 = A + (size_t)ar1 * K + (s1 & 3) * 8;
    const bf16* gb0 = Bt + (size_t)(n0 + (s0 >> 2)) * K + (s0 & 3) * 8;
    const bf16* gb1 = Bt + (size_t)(n0 + (s1 >> 2)) * K + (s1 & 3) * 8;
    const int lofs0 = (tid & ~63) * 8;
    const int lofs1 = 2048 + (tid & ~63) * 8;

    __builtin_amdgcn_global_load_lds(AS1C(ga0), AS3(&As[0][lofs0]), 16, 0, 0);
    __builtin_amdgcn_global_load_lds(AS1C(ga1), AS3(&As[0][lofs1]), 16, 0, 0);
    __builtin_amdgcn_global_load_lds(AS1C(gb0), AS3(&Bs[0][lofs0]), 16, 0, 0);
    __builtin_amdgcn_global_load_lds(AS1C(gb1), AS3(&Bs[0][lofs1]), 16, 0, 0);

    const int NIT = K >> 5;
    for (int k = 0; k < NIT; ++k) {
        const int buf = k & 1;
        __syncthreads();
        if (k + 1 < NIT) {
            const int ko = (k + 1) << 5;
            __builtin_amdgcn_global_load_lds(AS1C(ga0 + ko), AS3(&As[buf ^ 1][lofs0]), 16, 0, 0);
            __builtin_amdgcn_global_load_lds(AS1C(ga1 + ko), AS3(&As[buf ^ 1][lofs1]), 16, 0, 0);
            __builtin_amdgcn_global_load_lds(AS1C(gb0 + ko), AS3(&Bs[buf ^ 1][lofs0]), 16, 0, 0);
            __builtin_amdgcn_global_load_lds(AS1C(gb1 + ko), AS3(&Bs[buf ^ 1][lofs1]), 16, 0, 0);
        }
        bf16x8 af[4], bfr[4];
#pragma unroll
        for (int i = 0; i < 4; ++i)
            af[i] = *(const bf16x8*)(&As[buf][(wr + i * 16 + r15) * 32 + quad * 8]);
#pragma unroll
        for (int j = 0; j < 4; ++j)
            bfr[j] = *(const bf16x8*)(&Bs[buf][(wc + j * 16 + r15) * 32 + quad * 8]);
#pragma unroll
        for (int i = 0; i < 4; ++i)
#pragma unroll
            for (int j = 0; j < 4; ++j)
                acc[i][j] = __builtin_amdgcn_mfma_f32_16x16x32_bf16(af[i], bfr[j], acc[i][j], 0, 0, 0);
    }

#pragma unroll
    for (int i = 0; i < 4; ++i) {
#pragma unroll
        for (int r = 0; r < 4; ++r) {
            int grow = m0 + wr + i * 16 + quad * 4 + r;
            if (grow >= M) continue;
            float rs = HAS_RS ? rowscale[grow] : 1.f;
#pragma unroll
            for (int j = 0; j < 4; ++j) {
                int gcol = n0 + wc + j * 16 + r15;
                float v = acc[i][j][r];
                if (HAS_BIAS) v += rs * bias[gcol];
                if (RELU) v = fmaxf(v, 0.f);
                if (WF32) C[(size_t)grow * N + gcol] = v;
                if (WB16) Cb[(size_t)grow * N + gcol] = (bf16)v;
            }
        }
    }
}

// ---------------- 256x128 8-phase-style MFMA GEMM, mod-3 triple buffer ----------------
// BM=256, BN=128, BK=64, 8 waves (4M x 2N, 64x64 per wave), 512 threads.
// LDS 144 KiB: A 3 bufs x 32 KB (two 128-row halves) + B 3 bufs x 16 KB.
// 2 phases per K-tile, 16 MFMA per phase (same per-barrier MFMA mass as the
// 256^2 template). Staging runs 2 tiles ahead (6 units = 12 loads in flight),
// single counted s_waitcnt vmcnt(6) per K-tile -> loads never drain to 0.
// T2 row-XOR swizzle (seg^ (row&7)) applied on global source (linear LDS dest
// for global_load_lds) + same XOR on ds_read addresses -> 0 bank conflicts.
// T1 bijective XCD chunk swizzle (grid size % 8 == 0 by construction).
template <int RELU, int HAS_BIAS, int HAS_RS, int WF32, int WB16>
__global__ __launch_bounds__(512, 2) void mgemm_big_kernel(const bf16* __restrict__ A,
                                                           const bf16* __restrict__ Bt,
                                                           float* __restrict__ C,
                                                           bf16* __restrict__ Cb,
                                                           const float* __restrict__ bias,
                                                           const float* __restrict__ rowscale,
                                                           int M, int N, int K) {
    __shared__ bf16 lds[73728];  // 144 KiB: A at 0 (6*8192), B at 49152 (3*8192)
    const int tid = threadIdx.x;
    const int wave = tid >> 6, lane = tid & 63;
    const int wm = wave >> 1, wn = wave & 1;  // 4M x 2N
    const int quad = lane >> 4, r15 = lane & 15;

    // ---- T1: bijective XCD chunk swizzle (requires nwg % 8 == 0) ----
    const int nx = gridDim.x;
    const int nwg = nx * gridDim.y;
    const int bid = blockIdx.x + blockIdx.y * nx;
    const int wg = (bid & 7) * (nwg >> 3) + (bid >> 3);
    const int bx = wg % nx, by = wg / nx;
    const int m0 = by * 256, n0 = bx * 128;

    // ---- staging pointers: pre-swizzled global source, linear LDS dest ----
    const int srow = tid >> 3;
    const int scol = ((tid & 7) ^ (srow & 7)) * 8;
    const bf16* pa[4];
    const bf16* pb[2];
#pragma unroll
    for (int v = 0; v < 4; ++v) {
        int ra = m0 + v * 64 + srow;
        ra = ra < M ? ra : M - 1;
        pa[v] = A + (size_t)ra * K + scol;
    }
#pragma unroll
    for (int q = 0; q < 2; ++q)
        pb[q] = Bt + (size_t)(n0 + q * 64 + srow) * K + scol;
    const int ldst = (tid & ~63) * 8;  // wave-uniform; HW adds lane*16B

    // ---- ds_read per-lane constants ----
    const int aHalf = wm >> 1;                       // which 128-row half
    const int aRowB = ((wm & 1) * 64 + r15) * 64;    // + mf*1024
    const int bRowB = (wn * 64 + r15) * 64;          // + nf*1024
    const int sg0 = (quad ^ (r15 & 7)) * 8;
    const int sg1 = sg0 ^ 32;

#define STAGE_A(b, h, kt)                                                                           \
    do {                                                                                            \
        __builtin_amdgcn_global_load_lds(AS1C(pa[(h)*2 + 0] + (kt)*64),                             \
                                         AS3(&lds[((b)*2 + (h)) * 8192 + ldst]), 16, 0, 0);         \
        __builtin_amdgcn_global_load_lds(AS1C(pa[(h)*2 + 1] + (kt)*64),                             \
                                         AS3(&lds[((b)*2 + (h)) * 8192 + 4096 + ldst]), 16, 0, 0);  \
    } while (0)
#define STAGE_B(b, kt)                                                                              \
    do {                                                                                            \
        __builtin_amdgcn_global_load_lds(AS1C(pb[0] + (kt)*64),                                     \
                                         AS3(&lds[49152 + (b)*8192 + ldst]), 16, 0, 0);             \
        __builtin_amdgcn_global_load_lds(AS1C(pb[1] + (kt)*64),                                     \
                                         AS3(&lds[49152 + (b)*8192 + 4096 + ldst]), 16, 0, 0);      \
    } while (0)
#define LD_A2(b, mfb)                                                              \
    do {                                                                           \
        _Pragma("unroll") for (int mi = 0; mi < 2; ++mi) {                         \
            const bf16* p = &lds[((b)*2 + aHalf) * 8192 + aRowB + ((mfb) + mi) * 1024]; \
            aF[mi * 2 + 0] = *(const bf16x8*)(p + sg0);                            \
            aF[mi * 2 + 1] = *(const bf16x8*)(p + sg1);                            \
        }                                                                          \
    } while (0)
#define LD_B8(b)                                                                   \
    do {                                                                           \
        _Pragma("unroll") for (int nf = 0; nf < 4; ++nf) {                         \
            const bf16* p = &lds[49152 + (b)*8192 + bRowB + nf * 1024];            \
            bF[nf * 2 + 0] = *(const bf16x8*)(p + sg0);                            \
            bF[nf * 2 + 1] = *(const bf16x8*)(p + sg1);                            \
        }                                                                          \
    } while (0)
#define MM2(mfb)                                                                                    \
    do {                                                                                            \
        _Pragma("unroll") for (int mi = 0; mi < 2; ++mi)                                            \
            _Pragma("unroll") for (int nf = 0; nf < 4; ++nf)                                        \
                _Pragma("unroll") for (int kh = 0; kh < 2; ++kh)                                    \
                    acc[(mfb) + mi][nf] = __builtin_amdgcn_mfma_f32_16x16x32_bf16(                  \
                        aF[mi * 2 + kh], bF[nf * 2 + kh], acc[(mfb) + mi][nf], 0, 0, 0);            \
    } while (0)
#define BAR() __builtin_amdgcn_s_barrier()
#define WLG() asm volatile("s_waitcnt lgkmcnt(0)")
#define WVM6() asm volatile("s_waitcnt vmcnt(6)")
#define PRIO(x) __builtin_amdgcn_s_setprio(x)

    f32x4 acc[4][4] = {};
    bf16x8 aF[4], bF[8];

    // prologue: stage tiles 0 (buf0) and 1 (buf1); wait tile 0 (oldest 6)
    STAGE_A(0, 0, 0); STAGE_A(0, 1, 0); STAGE_B(0, 0);
    STAGE_A(1, 0, 1); STAGE_A(1, 1, 1); STAGE_B(1, 1);
    WVM6();
    BAR();

    const int NT = K >> 6;  // K-tiles of 64 (16 for K=1024)
    int bt = 0, bs = 2;     // t%3, (t+2)%3
    for (int t = 0; t < NT; ++t) {
        // parity-preserving clamp: restage tile t-1's data into the same slot
        const int kt = (t + 2 < NT) ? (t + 2) : (t - 1);
        // phA: all B-frags + A-frags M0,M1 ; stage A(t+2)
        LD_B8(bt); LD_A2(bt, 0);
        STAGE_A(bs, 0, kt); STAGE_A(bs, 1, kt);
        BAR(); WLG(); PRIO(1); MM2(0); PRIO(0); BAR();
        // phB: A-frags M2,M3 ; stage B(t+2) ; counted tile-boundary wait
        LD_A2(bt, 2);
        STAGE_B(bs, kt);
        BAR(); WLG(); PRIO(1); MM2(2); PRIO(0); WVM6(); BAR();
        bt = (bt == 2) ? 0 : bt + 1;
        bs = (bs == 2) ? 0 : bs + 1;
    }

    // epilogue: C/D layout col=lane&15, row=quad*4+reg (m89-verified)
#pragma unroll
    for (int mf = 0; mf < 4; ++mf) {
#pragma unroll
        for (int r = 0; r < 4; ++r) {
            int grow = m0 + wm * 64 + mf * 16 + quad * 4 + r;
            if (grow >= M) continue;
            float rs = HAS_RS ? rowscale[grow] : 1.f;
#pragma unroll
            for (int nf = 0; nf < 4; ++nf) {
                int gcol = n0 + wn * 64 + nf * 16 + r15;
                float v = acc[mf][nf][r];
                if (HAS_BIAS) v += rs * bias[gcol];
                if (RELU) v = fmaxf(v, 0.f);
                if (WF32) C[(size_t)grow * N + gcol] = v;
                if (WB16) Cb[(size_t)grow * N + gcol] = (bf16)v;
            }
        }
    }
#undef STAGE_A
#undef STAGE_B
#undef LD_A2
#undef LD_B8
#undef MM2
#undef BAR
#undef WLG
#undef WVM6
#undef PRIO
}

// ---------------- CSR aggregation over CB[node][2048] = [Cn ; Bn] ----------------
__global__ __launch_bounds__(256) void gather_kernel(const int* __restrict__ offs,
                                                     const int* __restrict__ esrc,
                                                     const bf16* __restrict__ CB,
                                                     bf16* __restrict__ Sb) {
    int half = threadIdx.x >> 7;
    int t = threadIdx.x & 127;
    int node = blockIdx.x * 2 + half;
    int c = t * 8;
    int k0 = offs[node], k1 = offs[node + 1];
    bf16x8 cv = *(const bf16x8*)(CB + (size_t)node * 2048 + c);
    float cf[8], a[8];
#pragma unroll
    for (int i = 0; i < 8; ++i) { cf[i] = (float)cv[i]; a[i] = 0.f; }
    for (int k = k0; k < k1; ++k) {
        int s = esrc[k];
        bf16x8 bv = *(const bf16x8*)(CB + (size_t)s * 2048 + 1024 + c);
#pragma unroll
        for (int i = 0; i < 8; ++i) a[i] += fmaxf(cf[i] + (float)bv[i], 0.f);
    }
    bf16x8 o;
#pragma unroll
    for (int i = 0; i < 8; ++i) o[i] = (bf16)a[i];
    *(bf16x8*)(Sb + (size_t)node * HID + c) = o;
}

// ---------------- stable head via MFMA ----------------
__global__ __launch_bounds__(64) void stable_mfma_kernel(const bf16* __restrict__ hb,
                                                         const bf16* __restrict__ swt,
                                                         const float* __restrict__ sb,
                                                         float* __restrict__ out) {
    int m0 = blockIdx.x * 16;  // NN = 625*16 exact
    int lane = threadIdx.x;
    int quad = lane >> 4, r15 = lane & 15;
    f32x4 acc0 = {}, acc1 = {};
    const bf16* arow = hb + (size_t)(m0 + r15) * HID + quad * 8;
    const bf16* b0 = swt + (size_t)r15 * HID + quad * 8;
    const bf16* b1p = swt + (size_t)(16 + r15) * HID + quad * 8;
    for (int k0 = 0; k0 < HID; k0 += 32) {
        bf16x8 af = *(const bf16x8*)(arow + k0);
        bf16x8 bf0 = *(const bf16x8*)(b0 + k0);
        bf16x8 bf1 = *(const bf16x8*)(b1p + k0);
        acc0 = __builtin_amdgcn_mfma_f32_16x16x32_bf16(af, bf0, acc0, 0, 0, 0);
        acc1 = __builtin_amdgcn_mfma_f32_16x16x32_bf16(af, bf1, acc1, 0, 0, 0);
    }
#pragma unroll
    for (int r = 0; r < 4; ++r) {
        int grow = m0 + quad * 4 + r;
        out[(size_t)grow * SDIM + r15] = acc0[r] + sb[r15];
        if (r15 < 2) out[(size_t)grow * SDIM + 16 + r15] = acc1[r] + sb[16 + r15];
    }
}

// ---------------- ghost head stage 2 ----------------
__global__ __launch_bounds__(256) void ghost_kernel(const float* __restrict__ g1,
                                                    const float* __restrict__ gw2,
                                                    const float* __restrict__ gb2,
                                                    float* __restrict__ out) {
    int w = threadIdx.x >> 6, lane = threadIdx.x & 63;
    int row = blockIdx.x * 4 + w;  // NN = 2500*4 exact
    const float4 gv = *(const float4*)(g1 + (size_t)row * GHID + lane * 4);
    const float4 wv = *(const float4*)(gw2 + lane * 4);
    float v = gv.x * wv.x + gv.y * wv.y + gv.z * wv.z + gv.w * wv.w;
#pragma unroll
    for (int o = 32; o > 0; o >>= 1) v += __shfl_down(v, o, 64);
    if (lane == 0) out[row] = 1.f / (1.f + expf(-(v + gb2[0])));
}

extern "C" void kernel_launch(void* const* d_in, const int* in_sizes, int n_in,
                              void* d_out, int out_size, void* d_ws, size_t ws_size,
                              hipStream_t stream) {
    const float* x   = (const float*)d_in[0];
    const int*   ei  = (const int*)d_in[1];
    const float* pw  = (const float*)d_in[2];
    const float* W1  = (const float*)d_in[3];
    const float* b1  = (const float*)d_in[4];
    const float* W2  = (const float*)d_in[5];
    const float* b2  = (const float*)d_in[6];
    const float* gw1 = (const float*)d_in[7];
    const float* gb1 = (const float*)d_in[8];
    const float* gw2 = (const float*)d_in[9];
    const float* gb2 = (const float*)d_in[10];
    const float* sw  = (const float*)d_in[11];
    const float* sb  = (const float*)d_in[12];

    float* out    = (float*)d_out;
    float* ghost  = out;                  // [N,1]
    float* stable = out + NN;             // [N,18]
    float* h      = out + NN + NN * SDIM; // [N,HID] fp32 (final h output)

    const size_t H2 = (size_t)HID * HID;
    float* ws   = (float*)d_ws;
    float* g1   = ws;                                  // NN*GHID fp32
    float* degF = g1 + (size_t)NN * GHID;              // NN
    float* cb   = degF + NN;                           // 4*2048 fp32
    bf16* hb    = (bf16*)(cb + 4 * 2048);              // NN*HID
    bf16* Sb    = hb + (size_t)NN * HID;               // NN*HID
    bf16* CB    = Sb + (size_t)NN * HID;               // NN*2048
    bf16* WT    = CB + (size_t)NN * 2048;              // 4 * 2*H2  ([Wd;Wb]^T per layer)
    bf16* W2t   = WT + 8 * H2;                         // 4*H2
    bf16* gw1t  = W2t + 4 * H2;                        // GHID*HID
    bf16* swt   = gw1t + (size_t)GHID * HID;           // 32*1024
    int*  cnt    = (int*)(swt + 32 * 1024);
    int*  offs   = cnt + NN;
    int*  cursor = offs + NN + 1;
    int*  esrc   = cursor + NN;

    // ---- fused prep (weights transpose/convert + swt + cb + cnt zero) ----
    prep_kernel<<<dim3(8648), 256, 0, stream>>>(W1, W2, gw1, sw, b1, WT, W2t, gw1t, swt, cb, cnt);

    // ---- CSR build ----
    count_kernel<<<dim3((EE + 255) / 256), 256, 0, stream>>>(ei, cnt);
    scan_kernel<<<dim3(1), 256, 0, stream>>>(cnt, offs, cursor, degF);
    scatter_kernel<<<dim3((EE + 255) / 256), 256, 0, stream>>>(ei, cursor, esrc);

    // ---- h0 ----
    proj_kernel<<<dim3(HID / 256, NN), 256, 0, stream>>>(x, pw, hb);

    dim3 gbigcb(2048 / 128, (NN + 255) / 256);  // (16, 40) = 640 blocks, %8==0
    dim3 gbigw2(HID / 128, (NN + 255) / 256);   // (8, 40)  = 320 blocks, %8==0
    for (int l = 0; l < NLAYERS; ++l) {
        // CB = hb @ [Wd ; Wb]^T + [b1 ; 0]   (N = 2048, fused Cn/Bn)
        mgemm_big_kernel<0, 1, 0, 0, 1><<<gbigcb, 512, 0, stream>>>(
            hb, WT + (size_t)l * 2 * H2, nullptr, CB, cb + l * 2048, nullptr, NN, 2048, HID);
        // S = segment_sum(relu(Cn[dst]+Bn[src]))
        gather_kernel<<<dim3(NN / 2), 256, 0, stream>>>(offs, esrc, CB, Sb);
        // h = relu(S @ W2 + deg*b2); last layer also writes fp32 h to d_out
        if (l < NLAYERS - 1)
            mgemm_big_kernel<1, 1, 1, 0, 1><<<gbigw2, 512, 0, stream>>>(
                Sb, W2t + (size_t)l * H2, nullptr, hb, b2 + (size_t)l * HID, degF, NN, HID, HID);
        else
            mgemm_big_kernel<1, 1, 1, 1, 1><<<gbigw2, 512, 0, stream>>>(
                Sb, W2t + (size_t)l * H2, h, hb, b2 + (size_t)l * HID, degF, NN, HID, HID);
    }

    // ---- ghost head (N=256: stays on 128^2 path, 158-block grid) ----
    mgemm_kernel<1, 1, 0, 1, 0><<<dim3(GHID / 128, (NN + 127) / 128), 256, 0, stream>>>(
        hb, gw1t, g1, nullptr, gb1, nullptr, NN, GHID, HID);
    ghost_kernel<<<dim3(NN / 4), 256, 0, stream>>>(g1, gw2, gb2, ghost);
    // ---- stable head (MFMA, 1 wave / 16 rows) ----
    stable_mfma_kernel<<<dim3(NN / 16), 64, 0, stream>>>(hb, swt, sb, stable);
}

// Round 3
// 743.559 us; speedup vs baseline: 1.0924x; 1.0924x over previous
//
#include <hip/hip_runtime.h>
#include <hip/hip_bf16.h>
#include <math.h>

#define NN 10000
#define EE 80000
#define SDIM 18
#define HID 1024
#define NLAYERS 4
#define GHID 256

typedef __bf16 bf16;
typedef __bf16 bf16x8 __attribute__((ext_vector_type(8)));
typedef __bf16 bf16x4 __attribute__((ext_vector_type(4)));
typedef float f32x4 __attribute__((ext_vector_type(4)));

#define AS1C(p) ((const __attribute__((address_space(1))) void*)(p))
#define AS3(p)  ((__attribute__((address_space(3))) void*)(p))

// ---------------- CSR build: count ----------------
__global__ void count_kernel(const int* __restrict__ ei, int* __restrict__ cnt) {
    int e = blockIdx.x * 256 + threadIdx.x;
    if (e < EE) atomicAdd(&cnt[ei[EE + e]], 1);
}

// ---------------- CSR build: exclusive scan (single block) ----------------
__global__ __launch_bounds__(256) void scan_kernel(const int* __restrict__ cnt,
                                                   int* __restrict__ offs,
                                                   int* __restrict__ cursor,
                                                   float* __restrict__ degF) {
    const int CH = 40;  // 256*40 = 10240 >= NN
    __shared__ int partial[256];
    int t = threadIdx.x;
    int base = t * CH;
    int local[CH];
    int sum = 0;
#pragma unroll
    for (int i = 0; i < CH; ++i) {
        int idx = base + i;
        int v = (idx < NN) ? cnt[idx] : 0;
        local[i] = sum;
        sum += v;
    }
    partial[t] = sum;
    __syncthreads();
    for (int off = 1; off < 256; off <<= 1) {
        int v = (t >= off) ? partial[t - off] : 0;
        __syncthreads();
        partial[t] += v;
        __syncthreads();
    }
    int excl = (t == 0) ? 0 : partial[t - 1];
#pragma unroll
    for (int i = 0; i < CH; ++i) {
        int idx = base + i;
        if (idx < NN) {
            int o = excl + local[i];
            offs[idx] = o;
            cursor[idx] = o;
            degF[idx] = (float)cnt[idx];
        }
    }
    if (t == 255) offs[NN] = partial[255];
}

// ---------------- CSR build: scatter edge sources ----------------
__global__ void scatter_kernel(const int* __restrict__ ei, int* __restrict__ cursor,
                               int* __restrict__ esrc) {
    int e = blockIdx.x * 256 + threadIdx.x;
    if (e < EE) {
        int dst = ei[EE + e];
        int pos = atomicAdd(&cursor[dst], 1);
        esrc[pos] = ei[e];
    }
}

// ---------------- fused prep: all weight transposes + swt + cb + cnt-zero ----------------
__global__ __launch_bounds__(256) void prep_kernel(const float* __restrict__ W1,
                                                   const float* __restrict__ W2,
                                                   const float* __restrict__ gw1,
                                                   const float* __restrict__ sw,
                                                   const float* __restrict__ b1,
                                                   bf16* __restrict__ WT,
                                                   bf16* __restrict__ W2t,
                                                   bf16* __restrict__ gw1t,
                                                   bf16* __restrict__ swt,
                                                   float* __restrict__ cb,
                                                   int* __restrict__ cnt) {
    __shared__ float td[32][33];
    __shared__ float tb[32][33];
    const size_t H2 = (size_t)HID * HID;
    int b = blockIdx.x;
    int tx = threadIdx.x & 31, ty = threadIdx.x >> 5;  // (32,8)

    if (b < 4096) {  // W1 fused diff transpose
        int l = b >> 10, r = b & 1023;
        int bx = (r & 31) * 32, by = (r >> 5) * 32;
        const float* s = W1 + (size_t)l * 2 * H2;
        bf16* d = WT + (size_t)l * 2 * H2;
#pragma unroll
        for (int r4 = 0; r4 < 4; ++r4) {
            int row = by + ty + r4 * 8;
            float vt = s[(size_t)row * HID + bx + tx];
            float vb = s[H2 + (size_t)row * HID + bx + tx];
            td[ty + r4 * 8][tx] = vt - vb;
            tb[ty + r4 * 8][tx] = vb;
        }
        __syncthreads();
#pragma unroll
        for (int r4 = 0; r4 < 4; ++r4) {
            int orow = bx + ty + r4 * 8;
            d[(size_t)orow * HID + by + tx] = (bf16)td[tx][ty + r4 * 8];
            d[(size_t)(HID + orow) * HID + by + tx] = (bf16)tb[tx][ty + r4 * 8];
        }
    } else if (b < 8192) {  // W2 transpose
        int sub = b - 4096;
        int l = sub >> 10, r = sub & 1023;
        int bx = (r & 31) * 32, by = (r >> 5) * 32;
        const float* s = W2 + (size_t)l * H2;
        bf16* d = W2t + (size_t)l * H2;
#pragma unroll
        for (int r4 = 0; r4 < 4; ++r4) {
            int row = by + ty + r4 * 8;
            td[ty + r4 * 8][tx] = s[(size_t)row * HID + bx + tx];
        }
        __syncthreads();
#pragma unroll
        for (int r4 = 0; r4 < 4; ++r4) {
            int orow = bx + ty + r4 * 8;
            d[(size_t)orow * HID + by + tx] = (bf16)td[tx][ty + r4 * 8];
        }
    } else if (b < 8448) {  // gw1 [1024][256] -> gw1t [256][1024]
        int sub = b - 8192;
        int bx = (sub & 7) * 32, by = (sub >> 3) * 32;
#pragma unroll
        for (int r4 = 0; r4 < 4; ++r4) {
            int row = by + ty + r4 * 8;
            td[ty + r4 * 8][tx] = gw1[(size_t)row * GHID + bx + tx];
        }
        __syncthreads();
#pragma unroll
        for (int r4 = 0; r4 < 4; ++r4) {
            int orow = bx + ty + r4 * 8;
            gw1t[(size_t)orow * HID + by + tx] = (bf16)td[tx][ty + r4 * 8];
        }
    } else if (b < 8576) {  // swt[32][1024] = sw[1024][18]^T zero-padded
        int i = (b - 8448) * 256 + threadIdx.x;
        int n = i >> 10, k = i & 1023;
        swt[i] = (bf16)(n < SDIM ? sw[k * SDIM + n] : 0.f);
    } else if (b < 8608) {  // cb[l][2048] = [b1[l] ; 0]
        int i = (b - 8576) * 256 + threadIdx.x;
        int l = i >> 11, c = i & 2047;
        cb[i] = (c < HID) ? b1[l * HID + c] : 0.f;
    } else {  // cnt zero
        int i = (b - 8608) * 256 + threadIdx.x;
        if (i < NN) cnt[i] = 0;
    }
}

// ---------------- h0 = sin(x@pw)*cos(x@pw) -> bf16 ----------------
__global__ __launch_bounds__(256) void proj_kernel(const float* __restrict__ x,
                                                   const float* __restrict__ pw,
                                                   bf16* __restrict__ hb) {
    int row = blockIdx.y;
    int col = blockIdx.x * 256 + threadIdx.x;
    __shared__ float xr[SDIM];
    if (threadIdx.x < SDIM) xr[threadIdx.x] = x[row * SDIM + threadIdx.x];
    __syncthreads();
    float acc = 0.f;
#pragma unroll
    for (int k = 0; k < SDIM; ++k) acc += xr[k] * pw[k * HID + col];
    hb[(size_t)row * HID + col] = (bf16)(sinf(acc) * cosf(acc));
}

// ---------------- bf16 MFMA GEMM: C = act(A @ Bt^T + rs*bias) ----------------
// Round-0 structure (128x128 tile, BK=32, 32KB LDS -> 5 blocks/CU, double
// buffer, stage-before-compute) + T2 bank-conflict fix:
//   LDS tile rows are 64B (4 x 16B segs); linear layout put 16-lane read
//   groups on 2 banks (8-way conflict, 5.2M cycles/dispatch). Store seg s of
//   row r at s ^ ((r>>1)&3): applied by PRE-SWIZZLING THE GLOBAL SOURCE
//   (global_load_lds dest must stay linear, rule #21) and XORing the ds_read
//   seg with the same function -> 8 distinct banks per 16-lane group (2-way
//   = free).
template <int RELU, int HAS_BIAS, int HAS_RS, int WF32, int WB16>
__global__ __launch_bounds__(256) void mgemm_kernel(const bf16* __restrict__ A,
                                                    const bf16* __restrict__ Bt,
                                                    float* __restrict__ C,
                                                    bf16* __restrict__ Cb,
                                                    const float* __restrict__ bias,
                                                    const float* __restrict__ rowscale,
                                                    int M, int N, int K) {
    __shared__ bf16 As[2][128 * 32];
    __shared__ bf16 Bs[2][128 * 32];
    const int tid = threadIdx.x;

    // ---- grouped block swizzle: 8 row-tiles per column sweep ----
    const int num_n = gridDim.x, num_m = gridDim.y;
    int bid = blockIdx.x + blockIdx.y * num_n;
    const int GROUP = 8;
    int width = GROUP * num_n;
    int group = bid / width;
    int rem = bid - group * width;
    int rows_ing = num_m - group * GROUP;
    rows_ing = rows_ing < GROUP ? rows_ing : GROUP;
    int by = group * GROUP + rem % rows_ing;
    int bx = rem / rows_ing;
    const int m0 = by * 128;
    const int n0 = bx * 128;

    const int wave = tid >> 6;
    const int wr = (wave >> 1) * 64, wc = (wave & 1) * 64;
    const int lane = tid & 63;
    const int quad = lane >> 4, r15 = lane & 15;

    f32x4 acc[4][4] = {};

    // staging slots: slot s in [0,512): tile-row s>>2, 16B kseg s&3.
    // T2: global seg pre-swizzled with (row>>1)&3 = (s>>3)&3.
    const int s0 = tid, s1 = 256 + tid;
    const int seg0 = ((s0 & 3) ^ ((s0 >> 3) & 3)) * 8;
    const int seg1 = ((s1 & 3) ^ ((s1 >> 3) & 3)) * 8;
    int ar0 = m0 + (s0 >> 2); ar0 = ar0 < M ? ar0 : M - 1;
    int ar1 = m0 + (s1 >> 2); ar1 = ar1 < M ? ar1 : M - 1;
    const bf16* ga0 = A + (size_t)ar0 * K + seg0;
    const bf16* ga1 = A + (size_t)ar1 * K + seg1;
    const bf16* gb0 = Bt + (size_t)(n0 + (s0 >> 2)) * K + seg0;
    const bf16* gb1 = Bt + (size_t)(n0 + (s1 >> 2)) * K + seg1;
    // wave-uniform LDS offsets (HW adds lane*16B)
    const int lofs0 = (tid & ~63) * 8;
    const int lofs1 = 2048 + (tid & ~63) * 8;

    // T2 read offsets: row r, want global seg q (=quad) -> LDS seg q^((r>>1)&3)
    int aoff[4], boff[4];
#pragma unroll
    for (int i = 0; i < 4; ++i) {
        int rA = wr + i * 16 + r15;
        aoff[i] = rA * 32 + (quad ^ ((rA >> 1) & 3)) * 8;
        int rB = wc + i * 16 + r15;
        boff[i] = rB * 32 + (quad ^ ((rB >> 1) & 3)) * 8;
    }

    // prologue: stage iter 0 into buf 0
    __builtin_amdgcn_global_load_lds(AS1C(ga0), AS3(&As[0][lofs0]), 16, 0, 0);
    __builtin_amdgcn_global_load_lds(AS1C(ga1), AS3(&As[0][lofs1]), 16, 0, 0);
    __builtin_amdgcn_global_load_lds(AS1C(gb0), AS3(&Bs[0][lofs0]), 16, 0, 0);
    __builtin_amdgcn_global_load_lds(AS1C(gb1), AS3(&Bs[0][lofs1]), 16, 0, 0);

    const int NIT = K >> 5;
    for (int k = 0; k < NIT; ++k) {
        const int buf = k & 1;
        // barrier: (a) vmcnt drain -> buf fully staged (issued one iter ago),
        //          (b) lgkm drain -> all waves' ds_reads of buf^1 finished.
        __syncthreads();
        if (k + 1 < NIT) {  // issue next tile's staging BEFORE compute
            const int ko = (k + 1) << 5;
            __builtin_amdgcn_global_load_lds(AS1C(ga0 + ko), AS3(&As[buf ^ 1][lofs0]), 16, 0, 0);
            __builtin_amdgcn_global_load_lds(AS1C(ga1 + ko), AS3(&As[buf ^ 1][lofs1]), 16, 0, 0);
            __builtin_amdgcn_global_load_lds(AS1C(gb0 + ko), AS3(&Bs[buf ^ 1][lofs0]), 16, 0, 0);
            __builtin_amdgcn_global_load_lds(AS1C(gb1 + ko), AS3(&Bs[buf ^ 1][lofs1]), 16, 0, 0);
        }
        bf16x8 af[4], bfr[4];
#pragma unroll
        for (int i = 0; i < 4; ++i)
            af[i] = *(const bf16x8*)(&As[buf][aoff[i]]);
#pragma unroll
        for (int j = 0; j < 4; ++j)
            bfr[j] = *(const bf16x8*)(&Bs[buf][boff[j]]);
#pragma unroll
        for (int i = 0; i < 4; ++i)
#pragma unroll
            for (int j = 0; j < 4; ++j)
                acc[i][j] = __builtin_amdgcn_mfma_f32_16x16x32_bf16(af[i], bfr[j], acc[i][j], 0, 0, 0);
    }

    // epilogue: C/D layout col=lane&15, row=quad*4+reg (m89-verified)
#pragma unroll
    for (int i = 0; i < 4; ++i) {
#pragma unroll
        for (int r = 0; r < 4; ++r) {
            int grow = m0 + wr + i * 16 + quad * 4 + r;
            if (grow >= M) continue;
            float rs = HAS_RS ? rowscale[grow] : 1.f;
#pragma unroll
            for (int j = 0; j < 4; ++j) {
                int gcol = n0 + wc + j * 16 + r15;
                float v = acc[i][j][r];
                if (HAS_BIAS) v += rs * bias[gcol];
                if (RELU) v = fmaxf(v, 0.f);
                if (WF32) C[(size_t)grow * N + gcol] = v;
                if (WB16) Cb[(size_t)grow * N + gcol] = (bf16)v;
            }
        }
    }
}

// ---------------- CSR aggregation over CB[node][2048] = [Cn ; Bn] ----------------
// 2 nodes/block; 128 threads x bf16x8 (16B/lane) per node.
__global__ __launch_bounds__(256) void gather_kernel(const int* __restrict__ offs,
                                                     const int* __restrict__ esrc,
                                                     const bf16* __restrict__ CB,
                                                     bf16* __restrict__ Sb) {
    int half = threadIdx.x >> 7;
    int t = threadIdx.x & 127;
    int node = blockIdx.x * 2 + half;
    int c = t * 8;
    int k0 = offs[node], k1 = offs[node + 1];
    bf16x8 cv = *(const bf16x8*)(CB + (size_t)node * 2048 + c);
    float cf[8], a[8];
#pragma unroll
    for (int i = 0; i < 8; ++i) { cf[i] = (float)cv[i]; a[i] = 0.f; }
    for (int k = k0; k < k1; ++k) {
        int s = esrc[k];
        bf16x8 bv = *(const bf16x8*)(CB + (size_t)s * 2048 + 1024 + c);
#pragma unroll
        for (int i = 0; i < 8; ++i) a[i] += fmaxf(cf[i] + (float)bv[i], 0.f);
    }
    bf16x8 o;
#pragma unroll
    for (int i = 0; i < 8; ++i) o[i] = (bf16)a[i];
    *(bf16x8*)(Sb + (size_t)node * HID + c) = o;
}

// ---------------- stable head via MFMA: out[16 rows][18] = hb_tile @ swt^T + sb ----------------
__global__ __launch_bounds__(64) void stable_mfma_kernel(const bf16* __restrict__ hb,
                                                         const bf16* __restrict__ swt,
                                                         const float* __restrict__ sb,
                                                         float* __restrict__ out) {
    int m0 = blockIdx.x * 16;  // NN = 625*16 exact
    int lane = threadIdx.x;
    int quad = lane >> 4, r15 = lane & 15;
    f32x4 acc0 = {}, acc1 = {};
    const bf16* arow = hb + (size_t)(m0 + r15) * HID + quad * 8;
    const bf16* b0 = swt + (size_t)r15 * HID + quad * 8;
    const bf16* b1p = swt + (size_t)(16 + r15) * HID + quad * 8;
    for (int k0 = 0; k0 < HID; k0 += 32) {
        bf16x8 af = *(const bf16x8*)(arow + k0);
        bf16x8 bf0 = *(const bf16x8*)(b0 + k0);
        bf16x8 bf1 = *(const bf16x8*)(b1p + k0);
        acc0 = __builtin_amdgcn_mfma_f32_16x16x32_bf16(af, bf0, acc0, 0, 0, 0);
        acc1 = __builtin_amdgcn_mfma_f32_16x16x32_bf16(af, bf1, acc1, 0, 0, 0);
    }
#pragma unroll
    for (int r = 0; r < 4; ++r) {
        int grow = m0 + quad * 4 + r;
        out[(size_t)grow * SDIM + r15] = acc0[r] + sb[r15];
        if (r15 < 2) out[(size_t)grow * SDIM + 16 + r15] = acc1[r] + sb[16 + r15];
    }
}

// ---------------- ghost head stage 2: sigmoid(g1 @ gw2 + gb2), wave per row ----------------
__global__ __launch_bounds__(256) void ghost_kernel(const float* __restrict__ g1,
                                                    const float* __restrict__ gw2,
                                                    const float* __restrict__ gb2,
                                                    float* __restrict__ out) {
    int w = threadIdx.x >> 6, lane = threadIdx.x & 63;
    int row = blockIdx.x * 4 + w;  // NN = 2500*4 exact
    const float4 gv = *(const float4*)(g1 + (size_t)row * GHID + lane * 4);
    const float4 wv = *(const float4*)(gw2 + lane * 4);
    float v = gv.x * wv.x + gv.y * wv.y + gv.z * wv.z + gv.w * wv.w;
#pragma unroll
    for (int o = 32; o > 0; o >>= 1) v += __shfl_down(v, o, 64);
    if (lane == 0) out[row] = 1.f / (1.f + expf(-(v + gb2[0])));
}

extern "C" void kernel_launch(void* const* d_in, const int* in_sizes, int n_in,
                              void* d_out, int out_size, void* d_ws, size_t ws_size,
                              hipStream_t stream) {
    const float* x   = (const float*)d_in[0];
    const int*   ei  = (const int*)d_in[1];
    const float* pw  = (const float*)d_in[2];
    const float* W1  = (const float*)d_in[3];
    const float* b1  = (const float*)d_in[4];
    const float* W2  = (const float*)d_in[5];
    const float* b2  = (const float*)d_in[6];
    const float* gw1 = (const float*)d_in[7];
    const float* gb1 = (const float*)d_in[8];
    const float* gw2 = (const float*)d_in[9];
    const float* gb2 = (const float*)d_in[10];
    const float* sw  = (const float*)d_in[11];
    const float* sb  = (const float*)d_in[12];

    float* out    = (float*)d_out;
    float* ghost  = out;                  // [N,1]
    float* stable = out + NN;             // [N,18]
    float* h      = out + NN + NN * SDIM; // [N,HID] fp32 (final h output)

    const size_t H2 = (size_t)HID * HID;
    float* ws   = (float*)d_ws;
    float* g1   = ws;                                  // NN*GHID fp32
    float* degF = g1 + (size_t)NN * GHID;              // NN
    float* cb   = degF + NN;                           // 4*2048 fp32
    bf16* hb    = (bf16*)(cb + 4 * 2048);              // NN*HID
    bf16* Sb    = hb + (size_t)NN * HID;               // NN*HID
    bf16* CB    = Sb + (size_t)NN * HID;               // NN*2048
    bf16* WT    = CB + (size_t)NN * 2048;              // 4 * 2*H2  ([Wd;Wb]^T per layer)
    bf16* W2t   = WT + 8 * H2;                         // 4*H2
    bf16* gw1t  = W2t + 4 * H2;                        // GHID*HID
    bf16* swt   = gw1t + (size_t)GHID * HID;           // 32*1024
    int*  cnt    = (int*)(swt + 32 * 1024);
    int*  offs   = cnt + NN;
    int*  cursor = offs + NN + 1;
    int*  esrc   = cursor + NN;

    // ---- fused prep (weights transpose/convert + swt + cb + cnt zero) ----
    prep_kernel<<<dim3(8648), 256, 0, stream>>>(W1, W2, gw1, sw, b1, WT, W2t, gw1t, swt, cb, cnt);

    // ---- CSR build ----
    count_kernel<<<dim3((EE + 255) / 256), 256, 0, stream>>>(ei, cnt);
    scan_kernel<<<dim3(1), 256, 0, stream>>>(cnt, offs, cursor, degF);
    scatter_kernel<<<dim3((EE + 255) / 256), 256, 0, stream>>>(ei, cursor, esrc);

    // ---- h0 ----
    proj_kernel<<<dim3(HID / 256, NN), 256, 0, stream>>>(x, pw, hb);

    dim3 gfused(2048 / 128, (NN + 127) / 128);  // (16, 79)
    dim3 gw2g(HID / 128, (NN + 127) / 128);     // (8, 79)
    for (int l = 0; l < NLAYERS; ++l) {
        // CB = hb @ [Wd ; Wb]^T + [b1 ; 0]   (N = 2048, fused Cn/Bn)
        mgemm_kernel<0, 1, 0, 0, 1><<<gfused, 256, 0, stream>>>(
            hb, WT + (size_t)l * 2 * H2, nullptr, CB, cb + l * 2048, nullptr, NN, 2048, HID);
        // S = segment_sum(relu(Cn[dst]+Bn[src]))
        gather_kernel<<<dim3(NN / 2), 256, 0, stream>>>(offs, esrc, CB, Sb);
        // h = relu(S @ W2 + deg*b2); last layer also writes fp32 h to d_out
        if (l < NLAYERS - 1)
            mgemm_kernel<1, 1, 1, 0, 1><<<gw2g, 256, 0, stream>>>(
                Sb, W2t + (size_t)l * H2, nullptr, hb, b2 + (size_t)l * HID, degF, NN, HID, HID);
        else
            mgemm_kernel<1, 1, 1, 1, 1><<<gw2g, 256, 0, stream>>>(
                Sb, W2t + (size_t)l * H2, h, hb, b2 + (size_t)l * HID, degF, NN, HID, HID);
    }

    // ---- ghost head ----
    mgemm_kernel<1, 1, 0, 1, 0><<<dim3(GHID / 128, (NN + 127) / 128), 256, 0, stream>>>(
        hb, gw1t, g1, nullptr, gb1, nullptr, NN, GHID, HID);
    ghost_kernel<<<dim3(NN / 4), 256, 0, stream>>>(g1, gw2, gb2, ghost);
    // ---- stable head (MFMA, 1 wave / 16 rows) ----
    stable_mfma_kernel<<<dim3(NN / 16), 64, 0, stream>>>(hb, swt, sb, stable);
}

// Round 5
// 720.690 us; speedup vs baseline: 1.1271x; 1.0317x over previous
//
#include <hip/hip_runtime.h>
#include <hip/hip_bf16.h>
#include <math.h>

#define NN 10000
#define EE 80000
#define SDIM 18
#define HID 1024
#define NLAYERS 4
#define GHID 256

typedef __bf16 bf16;
typedef __bf16 bf16x8 __attribute__((ext_vector_type(8)));
typedef __bf16 bf16x4 __attribute__((ext_vector_type(4)));
typedef float f32x4 __attribute__((ext_vector_type(4)));

#define AS1C(p) ((const __attribute__((address_space(1))) void*)(p))
#define AS3(p)  ((__attribute__((address_space(3))) void*)(p))

// ---------------- CSR build: count ----------------
__global__ void count_kernel(const int* __restrict__ ei, int* __restrict__ cnt) {
    int e = blockIdx.x * 256 + threadIdx.x;
    if (e < EE) atomicAdd(&cnt[ei[EE + e]], 1);
}

// ---------------- CSR build: exclusive scan (single block) ----------------
__global__ __launch_bounds__(256) void scan_kernel(const int* __restrict__ cnt,
                                                   int* __restrict__ offs,
                                                   int* __restrict__ cursor,
                                                   float* __restrict__ degF) {
    const int CH = 40;  // 256*40 = 10240 >= NN
    __shared__ int partial[256];
    int t = threadIdx.x;
    int base = t * CH;
    int local[CH];
    int sum = 0;
#pragma unroll
    for (int i = 0; i < CH; ++i) {
        int idx = base + i;
        int v = (idx < NN) ? cnt[idx] : 0;
        local[i] = sum;
        sum += v;
    }
    partial[t] = sum;
    __syncthreads();
    for (int off = 1; off < 256; off <<= 1) {
        int v = (t >= off) ? partial[t - off] : 0;
        __syncthreads();
        partial[t] += v;
        __syncthreads();
    }
    int excl = (t == 0) ? 0 : partial[t - 1];
#pragma unroll
    for (int i = 0; i < CH; ++i) {
        int idx = base + i;
        if (idx < NN) {
            int o = excl + local[i];
            offs[idx] = o;
            cursor[idx] = o;
            degF[idx] = (float)cnt[idx];
        }
    }
    if (t == 255) offs[NN] = partial[255];
}

// ---------------- CSR build: scatter edge sources ----------------
__global__ void scatter_kernel(const int* __restrict__ ei, int* __restrict__ cursor,
                               int* __restrict__ esrc) {
    int e = blockIdx.x * 256 + threadIdx.x;
    if (e < EE) {
        int dst = ei[EE + e];
        int pos = atomicAdd(&cursor[dst], 1);
        esrc[pos] = ei[e];
    }
}

// ---------------- fused prep: all weight transposes + swt + cb + cnt-zero ----------------
__global__ __launch_bounds__(256) void prep_kernel(const float* __restrict__ W1,
                                                   const float* __restrict__ W2,
                                                   const float* __restrict__ gw1,
                                                   const float* __restrict__ sw,
                                                   const float* __restrict__ b1,
                                                   bf16* __restrict__ WT,
                                                   bf16* __restrict__ W2t,
                                                   bf16* __restrict__ gw1t,
                                                   bf16* __restrict__ swt,
                                                   float* __restrict__ cb,
                                                   int* __restrict__ cnt) {
    __shared__ float td[32][33];
    __shared__ float tb[32][33];
    const size_t H2 = (size_t)HID * HID;
    int b = blockIdx.x;
    int tx = threadIdx.x & 31, ty = threadIdx.x >> 5;  // (32,8)

    if (b < 4096) {  // W1 fused diff transpose
        int l = b >> 10, r = b & 1023;
        int bx = (r & 31) * 32, by = (r >> 5) * 32;
        const float* s = W1 + (size_t)l * 2 * H2;
        bf16* d = WT + (size_t)l * 2 * H2;
#pragma unroll
        for (int r4 = 0; r4 < 4; ++r4) {
            int row = by + ty + r4 * 8;
            float vt = s[(size_t)row * HID + bx + tx];
            float vb = s[H2 + (size_t)row * HID + bx + tx];
            td[ty + r4 * 8][tx] = vt - vb;
            tb[ty + r4 * 8][tx] = vb;
        }
        __syncthreads();
#pragma unroll
        for (int r4 = 0; r4 < 4; ++r4) {
            int orow = bx + ty + r4 * 8;
            d[(size_t)orow * HID + by + tx] = (bf16)td[tx][ty + r4 * 8];
            d[(size_t)(HID + orow) * HID + by + tx] = (bf16)tb[tx][ty + r4 * 8];
        }
    } else if (b < 8192) {  // W2 transpose
        int sub = b - 4096;
        int l = sub >> 10, r = sub & 1023;
        int bx = (r & 31) * 32, by = (r >> 5) * 32;
        const float* s = W2 + (size_t)l * H2;
        bf16* d = W2t + (size_t)l * H2;
#pragma unroll
        for (int r4 = 0; r4 < 4; ++r4) {
            int row = by + ty + r4 * 8;
            td[ty + r4 * 8][tx] = s[(size_t)row * HID + bx + tx];
        }
        __syncthreads();
#pragma unroll
        for (int r4 = 0; r4 < 4; ++r4) {
            int orow = bx + ty + r4 * 8;
            d[(size_t)orow * HID + by + tx] = (bf16)td[tx][ty + r4 * 8];
        }
    } else if (b < 8448) {  // gw1 [1024][256] -> gw1t [256][1024]
        int sub = b - 8192;
        int bx = (sub & 7) * 32, by = (sub >> 3) * 32;
#pragma unroll
        for (int r4 = 0; r4 < 4; ++r4) {
            int row = by + ty + r4 * 8;
            td[ty + r4 * 8][tx] = gw1[(size_t)row * GHID + bx + tx];
        }
        __syncthreads();
#pragma unroll
        for (int r4 = 0; r4 < 4; ++r4) {
            int orow = bx + ty + r4 * 8;
            gw1t[(size_t)orow * HID + by + tx] = (bf16)td[tx][ty + r4 * 8];
        }
    } else if (b < 8576) {  // swt[32][1024] = sw[1024][18]^T zero-padded
        int i = (b - 8448) * 256 + threadIdx.x;
        int n = i >> 10, k = i & 1023;
        swt[i] = (bf16)(n < SDIM ? sw[k * SDIM + n] : 0.f);
    } else if (b < 8608) {  // cb[l][2048] = [b1[l] ; 0]
        int i = (b - 8576) * 256 + threadIdx.x;
        int l = i >> 11, c = i & 2047;
        cb[i] = (c < HID) ? b1[l * HID + c] : 0.f;
    } else {  // cnt zero
        int i = (b - 8608) * 256 + threadIdx.x;
        if (i < NN) cnt[i] = 0;
    }
}

// ---------------- h0 = sin(x@pw)*cos(x@pw) -> bf16 ----------------
__global__ __launch_bounds__(256) void proj_kernel(const float* __restrict__ x,
                                                   const float* __restrict__ pw,
                                                   bf16* __restrict__ hb) {
    int row = blockIdx.y;
    int col = blockIdx.x * 256 + threadIdx.x;
    __shared__ float xr[SDIM];
    if (threadIdx.x < SDIM) xr[threadIdx.x] = x[row * SDIM + threadIdx.x];
    __syncthreads();
    float acc = 0.f;
#pragma unroll
    for (int k = 0; k < SDIM; ++k) acc += xr[k] * pw[k * HID + col];
    hb[(size_t)row * HID + col] = (bf16)(sinf(acc) * cosf(acc));
}

// ---------------- old 128x128 MFMA GEMM (ghost head only, N=256) ----------------
template <int RELU, int HAS_BIAS, int HAS_RS, int WF32, int WB16>
__global__ __launch_bounds__(256) void mgemm_kernel(const bf16* __restrict__ A,
                                                    const bf16* __restrict__ Bt,
                                                    float* __restrict__ C,
                                                    bf16* __restrict__ Cb,
                                                    const float* __restrict__ bias,
                                                    const float* __restrict__ rowscale,
                                                    int M, int N, int K) {
    __shared__ bf16 As[2][128 * 32];
    __shared__ bf16 Bs[2][128 * 32];
    const int tid = threadIdx.x;

    const int num_n = gridDim.x, num_m = gridDim.y;
    int bid = blockIdx.x + blockIdx.y * num_n;
    const int GROUP = 8;
    int width = GROUP * num_n;
    int group = bid / width;
    int rem = bid - group * width;
    int rows_ing = num_m - group * GROUP;
    rows_ing = rows_ing < GROUP ? rows_ing : GROUP;
    int by = group * GROUP + rem % rows_ing;
    int bx = rem / rows_ing;
    const int m0 = by * 128;
    const int n0 = bx * 128;

    const int wave = tid >> 6;
    const int wr = (wave >> 1) * 64, wc = (wave & 1) * 64;
    const int lane = tid & 63;
    const int quad = lane >> 4, r15 = lane & 15;

    f32x4 acc[4][4] = {};

    const int s0 = tid, s1 = 256 + tid;
    const int seg0 = ((s0 & 3) ^ ((s0 >> 3) & 3)) * 8;
    const int seg1 = ((s1 & 3) ^ ((s1 >> 3) & 3)) * 8;
    int ar0 = m0 + (s0 >> 2); ar0 = ar0 < M ? ar0 : M - 1;
    int ar1 = m0 + (s1 >> 2); ar1 = ar1 < M ? ar1 : M - 1;
    const bf16* ga0 = A + (size_t)ar0 * K + seg0;
    const bf16* ga1 = A + (size_t)ar1 * K + seg1;
    const bf16* gb0 = Bt + (size_t)(n0 + (s0 >> 2)) * K + seg0;
    const bf16* gb1 = Bt + (size_t)(n0 + (s1 >> 2)) * K + seg1;
    const int lofs0 = (tid & ~63) * 8;
    const int lofs1 = 2048 + (tid & ~63) * 8;

    int aoff[4], boff[4];
#pragma unroll
    for (int i = 0; i < 4; ++i) {
        int rA = wr + i * 16 + r15;
        aoff[i] = rA * 32 + (quad ^ ((rA >> 1) & 3)) * 8;
        int rB = wc + i * 16 + r15;
        boff[i] = rB * 32 + (quad ^ ((rB >> 1) & 3)) * 8;
    }

    __builtin_amdgcn_global_load_lds(AS1C(ga0), AS3(&As[0][lofs0]), 16, 0, 0);
    __builtin_amdgcn_global_load_lds(AS1C(ga1), AS3(&As[0][lofs1]), 16, 0, 0);
    __builtin_amdgcn_global_load_lds(AS1C(gb0), AS3(&Bs[0][lofs0]), 16, 0, 0);
    __builtin_amdgcn_global_load_lds(AS1C(gb1), AS3(&Bs[0][lofs1]), 16, 0, 0);

    const int NIT = K >> 5;
    for (int k = 0; k < NIT; ++k) {
        const int buf = k & 1;
        __syncthreads();
        if (k + 1 < NIT) {
            const int ko = (k + 1) << 5;
            __builtin_amdgcn_global_load_lds(AS1C(ga0 + ko), AS3(&As[buf ^ 1][lofs0]), 16, 0, 0);
            __builtin_amdgcn_global_load_lds(AS1C(ga1 + ko), AS3(&As[buf ^ 1][lofs1]), 16, 0, 0);
            __builtin_amdgcn_global_load_lds(AS1C(gb0 + ko), AS3(&Bs[buf ^ 1][lofs0]), 16, 0, 0);
            __builtin_amdgcn_global_load_lds(AS1C(gb1 + ko), AS3(&Bs[buf ^ 1][lofs1]), 16, 0, 0);
        }
        bf16x8 af[4], bfr[4];
#pragma unroll
        for (int i = 0; i < 4; ++i)
            af[i] = *(const bf16x8*)(&As[buf][aoff[i]]);
#pragma unroll
        for (int j = 0; j < 4; ++j)
            bfr[j] = *(const bf16x8*)(&Bs[buf][boff[j]]);
#pragma unroll
        for (int i = 0; i < 4; ++i)
#pragma unroll
            for (int j = 0; j < 4; ++j)
                acc[i][j] = __builtin_amdgcn_mfma_f32_16x16x32_bf16(af[i], bfr[j], acc[i][j], 0, 0, 0);
    }

#pragma unroll
    for (int i = 0; i < 4; ++i) {
#pragma unroll
        for (int r = 0; r < 4; ++r) {
            int grow = m0 + wr + i * 16 + quad * 4 + r;
            if (grow >= M) continue;
            float rs = HAS_RS ? rowscale[grow] : 1.f;
#pragma unroll
            for (int j = 0; j < 4; ++j) {
                int gcol = n0 + wc + j * 16 + r15;
                float v = acc[i][j][r];
                if (HAS_BIAS) v += rs * bias[gcol];
                if (RELU) v = fmaxf(v, 0.f);
                if (WF32) C[(size_t)grow * N + gcol] = v;
                if (WB16) Cb[(size_t)grow * N + gcol] = (bf16)v;
            }
        }
    }
}

// ---------------- 256x128 BK=32 triple-buffered counted-vmcnt MFMA GEMM ----------------
// 8 waves (4M x 2N, 64x64/wave), 512 threads. LDS 72 KiB -> 2 blocks/CU:
//   B bufs [3][128*32] @ elem 0, A bufs [3][256*32] @ elem 12288.
// Per K-tile (one phase): {8 ds_read_b128 ; stage tile t+2 (3 global_load_lds)
//   ; lgkmcnt(0) ; setprio(1) ; 16 MFMA ; setprio(0) ; s_waitcnt vmcnt(3) ;
//   s_barrier}. Staging runs 2 tiles ahead; vmcnt NEVER drains to 0 in the
// loop (T4). Buffer indices are COMPILE-TIME via hand-unrolled mod-3 (rule
// #20). T2 seg-XOR swizzle (seg ^ ((row>>1)&3)): pre-swizzled global source
// (linear global_load_lds dest, rule #21) + same XOR on ds_read addresses
// (R3-verified: 0 bank conflicts). Round-0 GROUP-8 block swizzle (lowest
// measured FETCH on this problem).
template <int RELU, int HAS_BIAS, int HAS_RS, int WF32, int WB16>
__global__ __launch_bounds__(512, 4) void mgemm3_kernel(const bf16* __restrict__ A,
                                                        const bf16* __restrict__ Bt,
                                                        float* __restrict__ C,
                                                        bf16* __restrict__ Cb,
                                                        const float* __restrict__ bias,
                                                        const float* __restrict__ rowscale,
                                                        int M, int N, int K) {
    __shared__ bf16 lds[36864];  // 72 KiB
    const int tid = threadIdx.x;
    const int wave = tid >> 6, lane = tid & 63;
    const int wm = wave >> 1, wn = wave & 1;  // 4M x 2N
    const int quad = lane >> 4, r15 = lane & 15;

    // ---- GROUP-8 block swizzle ----
    const int num_n = gridDim.x, num_m = gridDim.y;
    int bid = blockIdx.x + blockIdx.y * num_n;
    const int GROUP = 8;
    int width = GROUP * num_n;
    int group = bid / width;
    int rem = bid - group * width;
    int rows_ing = num_m - group * GROUP;
    rows_ing = rows_ing < GROUP ? rows_ing : GROUP;
    int by = group * GROUP + rem % rows_ing;
    int bx = rem / rows_ing;
    const int m0 = by * 256, n0 = bx * 128;

    // ---- staging: pre-swizzled global source, linear LDS dest ----
    const int strow = tid >> 2;  // 0..127
    const int segsw = ((tid & 3) ^ ((tid >> 3) & 3)) * 8;
    int ar0 = m0 + strow;        ar0 = ar0 < M ? ar0 : M - 1;
    int ar1 = m0 + 128 + strow;  ar1 = ar1 < M ? ar1 : M - 1;
    const bf16* ga0 = A + (size_t)ar0 * K + segsw;
    const bf16* ga1 = A + (size_t)ar1 * K + segsw;
    const bf16* gb  = Bt + (size_t)(n0 + strow) * K + segsw;
    const int ldst = (tid & ~63) * 8;  // wave-uniform elems; HW adds lane*16B

    // ---- ds_read per-lane offsets (elems, include swizzle) ----
    int aoff[4], boff[4];
#pragma unroll
    for (int i = 0; i < 4; ++i) {
        int rA = wm * 64 + i * 16 + r15;
        aoff[i] = 12288 + rA * 32 + (quad ^ ((rA >> 1) & 3)) * 8;
        int rB = wn * 64 + i * 16 + r15;
        boff[i] = rB * 32 + (quad ^ ((rB >> 1) & 3)) * 8;
    }

    f32x4 acc[4][4] = {};

#define STAGE3(bs, kt)                                                                                \
    do {                                                                                              \
        const int ko_ = (kt) << 5;                                                                    \
        __builtin_amdgcn_global_load_lds(AS1C(ga0 + ko_), AS3(&lds[12288 + (bs)*8192 + ldst]), 16, 0, 0); \
        __builtin_amdgcn_global_load_lds(AS1C(ga1 + ko_), AS3(&lds[12288 + (bs)*8192 + 4096 + ldst]), 16, 0, 0); \
        __builtin_amdgcn_global_load_lds(AS1C(gb + ko_), AS3(&lds[(bs)*4096 + ldst]), 16, 0, 0);      \
    } while (0)

    // prologue: stage tiles 0,1; wait tile 0 (3 of tile 1 stay in flight)
    STAGE3(0, 0);
    STAGE3(1, 1);
    asm volatile("s_waitcnt vmcnt(3)");
    __builtin_amdgcn_s_barrier();

    const int NT = K >> 5;  // 32 for K=1024 (requires NT >= 3)
    int t = 0;

#define TILE3(bi, bs)                                                                          \
    do {                                                                                       \
        int kt = (t + 2 < NT) ? (t + 2) : (t - 1); /* clamp: junk restage, count-preserving */ \
        bf16x8 aF[4], bF[4];                                                                   \
        _Pragma("unroll") for (int i = 0; i < 4; ++i)                                          \
            aF[i] = *(const bf16x8*)(&lds[(bi)*8192 + aoff[i]]);                               \
        _Pragma("unroll") for (int j = 0; j < 4; ++j)                                          \
            bF[j] = *(const bf16x8*)(&lds[(bi)*4096 + boff[j]]);                               \
        STAGE3(bs, kt);                                                                        \
        asm volatile("s_waitcnt lgkmcnt(0)");                                                  \
        __builtin_amdgcn_s_setprio(1);                                                         \
        _Pragma("unroll") for (int i = 0; i < 4; ++i)                                          \
            _Pragma("unroll") for (int j = 0; j < 4; ++j)                                      \
                acc[i][j] = __builtin_amdgcn_mfma_f32_16x16x32_bf16(aF[i], bF[j], acc[i][j], 0, 0, 0); \
        __builtin_amdgcn_s_setprio(0);                                                         \
        asm volatile("s_waitcnt vmcnt(3)"); /* tile t+1 staged; t+2 stays in flight */         \
        __builtin_amdgcn_s_barrier();                                                          \
        ++t;                                                                                   \
    } while (0)

    while (t + 3 <= NT) { TILE3(0, 2); TILE3(1, 0); TILE3(2, 1); }
    if (t < NT) TILE3(0, 2);
    if (t < NT) TILE3(1, 0);
#undef TILE3
#undef STAGE3

    // epilogue: C/D layout col=lane&15, row=quad*4+reg (m89-verified)
#pragma unroll
    for (int i = 0; i < 4; ++i) {
#pragma unroll
        for (int r = 0; r < 4; ++r) {
            int grow = m0 + wm * 64 + i * 16 + quad * 4 + r;
            if (grow >= M) continue;
            float rs = HAS_RS ? rowscale[grow] : 1.f;
#pragma unroll
            for (int j = 0; j < 4; ++j) {
                int gcol = n0 + wn * 64 + j * 16 + r15;
                float v = acc[i][j][r];
                if (HAS_BIAS) v += rs * bias[gcol];
                if (RELU) v = fmaxf(v, 0.f);
                if (WF32) C[(size_t)grow * N + gcol] = v;
                if (WB16) Cb[(size_t)grow * N + gcol] = (bf16)v;
            }
        }
    }
}

// ---------------- CSR aggregation over CB[node][2048] = [Cn ; Bn] ----------------
__global__ __launch_bounds__(256) void gather_kernel(const int* __restrict__ offs,
                                                     const int* __restrict__ esrc,
                                                     const bf16* __restrict__ CB,
                                                     bf16* __restrict__ Sb) {
    int half = threadIdx.x >> 7;
    int t = threadIdx.x & 127;
    int node = blockIdx.x * 2 + half;
    int c = t * 8;
    int k0 = offs[node], k1 = offs[node + 1];
    bf16x8 cv = *(const bf16x8*)(CB + (size_t)node * 2048 + c);
    float cf[8], a[8];
#pragma unroll
    for (int i = 0; i < 8; ++i) { cf[i] = (float)cv[i]; a[i] = 0.f; }
    for (int k = k0; k < k1; ++k) {
        int s = esrc[k];
        bf16x8 bv = *(const bf16x8*)(CB + (size_t)s * 2048 + 1024 + c);
#pragma unroll
        for (int i = 0; i < 8; ++i) a[i] += fmaxf(cf[i] + (float)bv[i], 0.f);
    }
    bf16x8 o;
#pragma unroll
    for (int i = 0; i < 8; ++i) o[i] = (bf16)a[i];
    *(bf16x8*)(Sb + (size_t)node * HID + c) = o;
}

// ---------------- stable head via MFMA ----------------
__global__ __launch_bounds__(64) void stable_mfma_kernel(const bf16* __restrict__ hb,
                                                         const bf16* __restrict__ swt,
                                                         const float* __restrict__ sb,
                                                         float* __restrict__ out) {
    int m0 = blockIdx.x * 16;  // NN = 625*16 exact
    int lane = threadIdx.x;
    int quad = lane >> 4, r15 = lane & 15;
    f32x4 acc0 = {}, acc1 = {};
    const bf16* arow = hb + (size_t)(m0 + r15) * HID + quad * 8;
    const bf16* b0 = swt + (size_t)r15 * HID + quad * 8;
    const bf16* b1p = swt + (size_t)(16 + r15) * HID + quad * 8;
    for (int k0 = 0; k0 < HID; k0 += 32) {
        bf16x8 af = *(const bf16x8*)(arow + k0);
        bf16x8 bf0 = *(const bf16x8*)(b0 + k0);
        bf16x8 bf1 = *(const bf16x8*)(b1p + k0);
        acc0 = __builtin_amdgcn_mfma_f32_16x16x32_bf16(af, bf0, acc0, 0, 0, 0);
        acc1 = __builtin_amdgcn_mfma_f32_16x16x32_bf16(af, bf1, acc1, 0, 0, 0);
    }
#pragma unroll
    for (int r = 0; r < 4; ++r) {
        int grow = m0 + quad * 4 + r;
        out[(size_t)grow * SDIM + r15] = acc0[r] + sb[r15];
        if (r15 < 2) out[(size_t)grow * SDIM + 16 + r15] = acc1[r] + sb[16 + r15];
    }
}

// ---------------- ghost head stage 2 ----------------
__global__ __launch_bounds__(256) void ghost_kernel(const float* __restrict__ g1,
                                                    const float* __restrict__ gw2,
                                                    const float* __restrict__ gb2,
                                                    float* __restrict__ out) {
    int w = threadIdx.x >> 6, lane = threadIdx.x & 63;
    int row = blockIdx.x * 4 + w;  // NN = 2500*4 exact
    const float4 gv = *(const float4*)(g1 + (size_t)row * GHID + lane * 4);
    const float4 wv = *(const float4*)(gw2 + lane * 4);
    float v = gv.x * wv.x + gv.y * wv.y + gv.z * wv.z + gv.w * wv.w;
#pragma unroll
    for (int o = 32; o > 0; o >>= 1) v += __shfl_down(v, o, 64);
    if (lane == 0) out[row] = 1.f / (1.f + expf(-(v + gb2[0])));
}

extern "C" void kernel_launch(void* const* d_in, const int* in_sizes, int n_in,
                              void* d_out, int out_size, void* d_ws, size_t ws_size,
                              hipStream_t stream) {
    const float* x   = (const float*)d_in[0];
    const int*   ei  = (const int*)d_in[1];
    const float* pw  = (const float*)d_in[2];
    const float* W1  = (const float*)d_in[3];
    const float* b1  = (const float*)d_in[4];
    const float* W2  = (const float*)d_in[5];
    const float* b2  = (const float*)d_in[6];
    const float* gw1 = (const float*)d_in[7];
    const float* gb1 = (const float*)d_in[8];
    const float* gw2 = (const float*)d_in[9];
    const float* gb2 = (const float*)d_in[10];
    const float* sw  = (const float*)d_in[11];
    const float* sb  = (const float*)d_in[12];

    float* out    = (float*)d_out;
    float* ghost  = out;                  // [N,1]
    float* stable = out + NN;             // [N,18]
    float* h      = out + NN + NN * SDIM; // [N,HID] fp32 (final h output)

    const size_t H2 = (size_t)HID * HID;
    float* ws   = (float*)d_ws;
    float* g1   = ws;                                  // NN*GHID fp32
    float* degF = g1 + (size_t)NN * GHID;              // NN
    float* cb   = degF + NN;                           // 4*2048 fp32
    bf16* hb    = (bf16*)(cb + 4 * 2048);              // NN*HID
    bf16* Sb    = hb + (size_t)NN * HID;               // NN*HID
    bf16* CB    = Sb + (size_t)NN * HID;               // NN*2048
    bf16* WT    = CB + (size_t)NN * 2048;              // 4 * 2*H2  ([Wd;Wb]^T per layer)
    bf16* W2t   = WT + 8 * H2;                         // 4*H2
    bf16* gw1t  = W2t + 4 * H2;                        // GHID*HID
    bf16* swt   = gw1t + (size_t)GHID * HID;           // 32*1024
    int*  cnt    = (int*)(swt + 32 * 1024);
    int*  offs   = cnt + NN;
    int*  cursor = offs + NN + 1;
    int*  esrc   = cursor + NN;

    // ---- fused prep (weights transpose/convert + swt + cb + cnt zero) ----
    prep_kernel<<<dim3(8648), 256, 0, stream>>>(W1, W2, gw1, sw, b1, WT, W2t, gw1t, swt, cb, cnt);

    // ---- CSR build ----
    count_kernel<<<dim3((EE + 255) / 256), 256, 0, stream>>>(ei, cnt);
    scan_kernel<<<dim3(1), 256, 0, stream>>>(cnt, offs, cursor, degF);
    scatter_kernel<<<dim3((EE + 255) / 256), 256, 0, stream>>>(ei, cursor, esrc);

    // ---- h0 ----
    proj_kernel<<<dim3(HID / 256, NN), 256, 0, stream>>>(x, pw, hb);

    dim3 gcbg(2048 / 128, (NN + 255) / 256);     // (16, 40) = 640 blocks
    dim3 gw2grid(HID / 128, (NN + 255) / 256);   // (8, 40)  = 320 blocks
    for (int l = 0; l < NLAYERS; ++l) {
        // CB = hb @ [Wd ; Wb]^T + [b1 ; 0]   (N = 2048, fused Cn/Bn)
        mgemm3_kernel<0, 1, 0, 0, 1><<<gcbg, 512, 0, stream>>>(
            hb, WT + (size_t)l * 2 * H2, nullptr, CB, cb + l * 2048, nullptr, NN, 2048, HID);
        // S = segment_sum(relu(Cn[dst]+Bn[src]))
        gather_kernel<<<dim3(NN / 2), 256, 0, stream>>>(offs, esrc, CB, Sb);
        // h = relu(S @ W2 + deg*b2); last layer also writes fp32 h to d_out
        if (l < NLAYERS - 1)
            mgemm3_kernel<1, 1, 1, 0, 1><<<gw2grid, 512, 0, stream>>>(
                Sb, W2t + (size_t)l * H2, nullptr, hb, b2 + (size_t)l * HID, degF, NN, HID, HID);
        else
            mgemm3_kernel<1, 1, 1, 1, 1><<<gw2grid, 512, 0, stream>>>(
                Sb, W2t + (size_t)l * H2, h, hb, b2 + (size_t)l * HID, degF, NN, HID, HID);
    }

    // ---- ghost head (N=256: old 128^2 path) ----
    mgemm_kernel<1, 1, 0, 1, 0><<<dim3(GHID / 128, (NN + 127) / 128), 256, 0, stream>>>(
        hb, gw1t, g1, nullptr, gb1, nullptr, NN, GHID, HID);
    ghost_kernel<<<dim3(NN / 4), 256, 0, stream>>>(g1, gw2, gb2, ghost);
    // ---- stable head (MFMA, 1 wave / 16 rows) ----
    stable_mfma_kernel<<<dim3(NN / 16), 64, 0, stream>>>(hb, swt, sb, stable);
}

// Round 7
// 716.134 us; speedup vs baseline: 1.1343x; 1.0064x over previous
//
#include <hip/hip_runtime.h>
#include <hip/hip_bf16.h>
#include <math.h>

#define NN 10000
#define EE 80000
#define SDIM 18
#define HID 1024
#define NLAYERS 4
#define GHID 256

typedef __bf16 bf16;
typedef __bf16 bf16x8 __attribute__((ext_vector_type(8)));
typedef __bf16 bf16x4 __attribute__((ext_vector_type(4)));
typedef float f32x4 __attribute__((ext_vector_type(4)));

#define AS1C(p) ((const __attribute__((address_space(1))) void*)(p))
#define AS3(p)  ((__attribute__((address_space(3))) void*)(p))

// ---------------- CSR build: count ----------------
__global__ void count_kernel(const int* __restrict__ ei, int* __restrict__ cnt) {
    int e = blockIdx.x * 256 + threadIdx.x;
    if (e < EE) atomicAdd(&cnt[ei[EE + e]], 1);
}

// ---------------- CSR build: exclusive scan (single block) ----------------
__global__ __launch_bounds__(256) void scan_kernel(const int* __restrict__ cnt,
                                                   int* __restrict__ offs,
                                                   int* __restrict__ cursor,
                                                   float* __restrict__ degF) {
    const int CH = 40;  // 256*40 = 10240 >= NN
    __shared__ int partial[256];
    int t = threadIdx.x;
    int base = t * CH;
    int local[CH];
    int sum = 0;
#pragma unroll
    for (int i = 0; i < CH; ++i) {
        int idx = base + i;
        int v = (idx < NN) ? cnt[idx] : 0;
        local[i] = sum;
        sum += v;
    }
    partial[t] = sum;
    __syncthreads();
    for (int off = 1; off < 256; off <<= 1) {
        int v = (t >= off) ? partial[t - off] : 0;
        __syncthreads();
        partial[t] += v;
        __syncthreads();
    }
    int excl = (t == 0) ? 0 : partial[t - 1];
#pragma unroll
    for (int i = 0; i < CH; ++i) {
        int idx = base + i;
        if (idx < NN) {
            int o = excl + local[i];
            offs[idx] = o;
            cursor[idx] = o;
            degF[idx] = (float)cnt[idx];
        }
    }
    if (t == 255) offs[NN] = partial[255];
}

// ---------------- CSR build: scatter edge sources ----------------
__global__ void scatter_kernel(const int* __restrict__ ei, int* __restrict__ cursor,
                               int* __restrict__ esrc) {
    int e = blockIdx.x * 256 + threadIdx.x;
    if (e < EE) {
        int dst = ei[EE + e];
        int pos = atomicAdd(&cursor[dst], 1);
        esrc[pos] = ei[e];
    }
}

// ---------------- fused prep: all weight transposes + swt + cb + cnt-zero ----------------
__global__ __launch_bounds__(256) void prep_kernel(const float* __restrict__ W1,
                                                   const float* __restrict__ W2,
                                                   const float* __restrict__ gw1,
                                                   const float* __restrict__ sw,
                                                   const float* __restrict__ b1,
                                                   bf16* __restrict__ WT,
                                                   bf16* __restrict__ W2t,
                                                   bf16* __restrict__ gw1t,
                                                   bf16* __restrict__ swt,
                                                   float* __restrict__ cb,
                                                   int* __restrict__ cnt) {
    __shared__ float td[32][33];
    __shared__ float tb[32][33];
    const size_t H2 = (size_t)HID * HID;
    int b = blockIdx.x;
    int tx = threadIdx.x & 31, ty = threadIdx.x >> 5;  // (32,8)

    if (b < 4096) {  // W1 fused diff transpose
        int l = b >> 10, r = b & 1023;
        int bx = (r & 31) * 32, by = (r >> 5) * 32;
        const float* s = W1 + (size_t)l * 2 * H2;
        bf16* d = WT + (size_t)l * 2 * H2;
#pragma unroll
        for (int r4 = 0; r4 < 4; ++r4) {
            int row = by + ty + r4 * 8;
            float vt = s[(size_t)row * HID + bx + tx];
            float vb = s[H2 + (size_t)row * HID + bx + tx];
            td[ty + r4 * 8][tx] = vt - vb;
            tb[ty + r4 * 8][tx] = vb;
        }
        __syncthreads();
#pragma unroll
        for (int r4 = 0; r4 < 4; ++r4) {
            int orow = bx + ty + r4 * 8;
            d[(size_t)orow * HID + by + tx] = (bf16)td[tx][ty + r4 * 8];
            d[(size_t)(HID + orow) * HID + by + tx] = (bf16)tb[tx][ty + r4 * 8];
        }
    } else if (b < 8192) {  // W2 transpose
        int sub = b - 4096;
        int l = sub >> 10, r = sub & 1023;
        int bx = (r & 31) * 32, by = (r >> 5) * 32;
        const float* s = W2 + (size_t)l * H2;
        bf16* d = W2t + (size_t)l * H2;
#pragma unroll
        for (int r4 = 0; r4 < 4; ++r4) {
            int row = by + ty + r4 * 8;
            td[ty + r4 * 8][tx] = s[(size_t)row * HID + bx + tx];
        }
        __syncthreads();
#pragma unroll
        for (int r4 = 0; r4 < 4; ++r4) {
            int orow = bx + ty + r4 * 8;
            d[(size_t)orow * HID + by + tx] = (bf16)td[tx][ty + r4 * 8];
        }
    } else if (b < 8448) {  // gw1 [1024][256] -> gw1t [256][1024]
        int sub = b - 8192;
        int bx = (sub & 7) * 32, by = (sub >> 3) * 32;
#pragma unroll
        for (int r4 = 0; r4 < 4; ++r4) {
            int row = by + ty + r4 * 8;
            td[ty + r4 * 8][tx] = gw1[(size_t)row * GHID + bx + tx];
        }
        __syncthreads();
#pragma unroll
        for (int r4 = 0; r4 < 4; ++r4) {
            int orow = bx + ty + r4 * 8;
            gw1t[(size_t)orow * HID + by + tx] = (bf16)td[tx][ty + r4 * 8];
        }
    } else if (b < 8576) {  // swt[32][1024] = sw[1024][18]^T zero-padded
        int i = (b - 8448) * 256 + threadIdx.x;
        int n = i >> 10, k = i & 1023;
        swt[i] = (bf16)(n < SDIM ? sw[k * SDIM + n] : 0.f);
    } else if (b < 8608) {  // cb[l][2048] = [b1[l] ; 0]
        int i = (b - 8576) * 256 + threadIdx.x;
        int l = i >> 11, c = i & 2047;
        cb[i] = (c < HID) ? b1[l * HID + c] : 0.f;
    } else {  // cnt zero
        int i = (b - 8608) * 256 + threadIdx.x;
        if (i < NN) cnt[i] = 0;
    }
}

// ---------------- h0 = sin(x@pw)*cos(x@pw) -> bf16 ----------------
__global__ __launch_bounds__(256) void proj_kernel(const float* __restrict__ x,
                                                   const float* __restrict__ pw,
                                                   bf16* __restrict__ hb) {
    int row = blockIdx.y;
    int col = blockIdx.x * 256 + threadIdx.x;
    __shared__ float xr[SDIM];
    if (threadIdx.x < SDIM) xr[threadIdx.x] = x[row * SDIM + threadIdx.x];
    __syncthreads();
    float acc = 0.f;
#pragma unroll
    for (int k = 0; k < SDIM; ++k) acc += xr[k] * pw[k * HID + col];
    hb[(size_t)row * HID + col] = (bf16)(sinf(acc) * cosf(acc));
}

// ---------------- 128x128 BK=32 triple-buffered counted-vmcnt MFMA GEMM ----------------
// 4 waves (2M x 2N, 64x64/wave), 256 threads. LDS 48 KiB -> 3 blocks/CU:
//   B bufs [3][128*32] @ elem 0, A bufs [3][128*32] @ elem 12288.
// R5-verified schedule at half the job size (finer grid packing: CB 1264 jobs
// / 768 slots, W2 632 / 768 single-wave). Per K-tile: {8 ds_read_b128 ;
// stage tile t+2 (4 global_load_lds) ; lgkmcnt(0) ; setprio(1) ; 16 MFMA ;
// setprio(0) ; s_waitcnt vmcnt(4) ; s_barrier}. vmcnt never drains to 0 in
// the loop (T4). Compile-time mod-3 buffers (rule #20). T2 seg-XOR swizzle
// (seg ^ ((row>>1)&3)) applied pre-swizzled on the global source (linear
// global_load_lds dest, rule #21) + same XOR on ds_read (R3: 0 conflicts).
// GROUP-8 block swizzle (round-0 measured 50 MB FETCH at this exact grid).
template <int RELU, int HAS_BIAS, int HAS_RS, int WF32, int WB16>
__global__ __launch_bounds__(256, 3) void mgemm3_kernel(const bf16* __restrict__ A,
                                                        const bf16* __restrict__ Bt,
                                                        float* __restrict__ C,
                                                        bf16* __restrict__ Cb,
                                                        const float* __restrict__ bias,
                                                        const float* __restrict__ rowscale,
                                                        int M, int N, int K) {
    __shared__ bf16 lds[24576];  // 48 KiB
    const int tid = threadIdx.x;
    const int wave = tid >> 6, lane = tid & 63;
    const int wm = wave >> 1, wn = wave & 1;  // 2M x 2N
    const int quad = lane >> 4, r15 = lane & 15;

    // ---- GROUP-8 block swizzle ----
    const int num_n = gridDim.x, num_m = gridDim.y;
    int bid = blockIdx.x + blockIdx.y * num_n;
    const int GROUP = 8;
    int width = GROUP * num_n;
    int group = bid / width;
    int rem = bid - group * width;
    int rows_ing = num_m - group * GROUP;
    rows_ing = rows_ing < GROUP ? rows_ing : GROUP;
    int by = group * GROUP + rem % rows_ing;
    int bx = rem / rows_ing;
    const int m0 = by * 128, n0 = bx * 128;

    // ---- staging: pre-swizzled global source, linear LDS dest ----
    // unit = 256 threads x 16B = 64 rows; tile = 2 units (rows 0-63, 64-127)
    const int strow = tid >> 2;  // 0..63
    const int segsw = ((tid & 3) ^ ((tid >> 3) & 3)) * 8;
    int ar0 = m0 + strow;       ar0 = ar0 < M ? ar0 : M - 1;
    int ar1 = m0 + 64 + strow;  ar1 = ar1 < M ? ar1 : M - 1;
    const bf16* ga0 = A + (size_t)ar0 * K + segsw;
    const bf16* ga1 = A + (size_t)ar1 * K + segsw;
    const bf16* gb0 = Bt + (size_t)(n0 + strow) * K + segsw;
    const bf16* gb1 = Bt + (size_t)(n0 + 64 + strow) * K + segsw;
    const int ldst = (tid & ~63) * 8;  // wave-uniform elems; HW adds lane*16B

    // ---- ds_read per-lane offsets (elems, include swizzle) ----
    int aoff[4], boff[4];
#pragma unroll
    for (int i = 0; i < 4; ++i) {
        int rA = wm * 64 + i * 16 + r15;
        aoff[i] = 12288 + rA * 32 + (quad ^ ((rA >> 1) & 3)) * 8;
        int rB = wn * 64 + i * 16 + r15;
        boff[i] = rB * 32 + (quad ^ ((rB >> 1) & 3)) * 8;
    }

    f32x4 acc[4][4] = {};

#define STAGE3(bs, kt)                                                                                   \
    do {                                                                                                 \
        const int ko_ = (kt) << 5;                                                                       \
        __builtin_amdgcn_global_load_lds(AS1C(ga0 + ko_), AS3(&lds[12288 + (bs)*4096 + ldst]), 16, 0, 0); \
        __builtin_amdgcn_global_load_lds(AS1C(ga1 + ko_), AS3(&lds[12288 + (bs)*4096 + 2048 + ldst]), 16, 0, 0); \
        __builtin_amdgcn_global_load_lds(AS1C(gb0 + ko_), AS3(&lds[(bs)*4096 + ldst]), 16, 0, 0);        \
        __builtin_amdgcn_global_load_lds(AS1C(gb1 + ko_), AS3(&lds[(bs)*4096 + 2048 + ldst]), 16, 0, 0); \
    } while (0)

    // prologue: stage tiles 0,1; wait tile 0 (4 of tile 1 stay in flight)
    STAGE3(0, 0);
    STAGE3(1, 1);
    asm volatile("s_waitcnt vmcnt(4)");
    __builtin_amdgcn_s_barrier();

    const int NT = K >> 5;  // 32 for K=1024 (requires NT >= 3)
    int t = 0;

#define TILE3(bi, bs)                                                                          \
    do {                                                                                       \
        int kt = (t + 2 < NT) ? (t + 2) : (t - 1); /* clamp: junk restage, count-preserving */ \
        bf16x8 aF[4], bF[4];                                                                   \
        _Pragma("unroll") for (int i = 0; i < 4; ++i)                                          \
            aF[i] = *(const bf16x8*)(&lds[(bi)*4096 + aoff[i]]);                               \
        _Pragma("unroll") for (int j = 0; j < 4; ++j)                                          \
            bF[j] = *(const bf16x8*)(&lds[(bi)*4096 + boff[j]]);                               \
        STAGE3(bs, kt);                                                                        \
        asm volatile("s_waitcnt lgkmcnt(0)");                                                  \
        __builtin_amdgcn_s_setprio(1);                                                         \
        _Pragma("unroll") for (int i = 0; i < 4; ++i)                                          \
            _Pragma("unroll") for (int j = 0; j < 4; ++j)                                      \
                acc[i][j] = __builtin_amdgcn_mfma_f32_16x16x32_bf16(aF[i], bF[j], acc[i][j], 0, 0, 0); \
        __builtin_amdgcn_s_setprio(0);                                                         \
        asm volatile("s_waitcnt vmcnt(4)"); /* tile t+1 staged; t+2 stays in flight */         \
        __builtin_amdgcn_s_barrier();                                                          \
        ++t;                                                                                   \
    } while (0)

    while (t + 3 <= NT) { TILE3(0, 2); TILE3(1, 0); TILE3(2, 1); }
    if (t < NT) TILE3(0, 2);
    if (t < NT) TILE3(1, 0);
#undef TILE3
#undef STAGE3

    // epilogue: C/D layout col=lane&15, row=quad*4+reg (m89-verified)
#pragma unroll
    for (int i = 0; i < 4; ++i) {
#pragma unroll
        for (int r = 0; r < 4; ++r) {
            int grow = m0 + wm * 64 + i * 16 + quad * 4 + r;
            if (grow >= M) continue;
            float rs = HAS_RS ? rowscale[grow] : 1.f;
#pragma unroll
            for (int j = 0; j < 4; ++j) {
                int gcol = n0 + wn * 64 + j * 16 + r15;
                float v = acc[i][j][r];
                if (HAS_BIAS) v += rs * bias[gcol];
                if (RELU) v = fmaxf(v, 0.f);
                if (WF32) C[(size_t)grow * N + gcol] = v;
                if (WB16) Cb[(size_t)grow * N + gcol] = (bf16)v;
            }
        }
    }
}

// ---------------- CSR aggregation over CB[node][2048] = [Cn ; Bn] ----------------
__global__ __launch_bounds__(256) void gather_kernel(const int* __restrict__ offs,
                                                     const int* __restrict__ esrc,
                                                     const bf16* __restrict__ CB,
                                                     bf16* __restrict__ Sb) {
    int half = threadIdx.x >> 7;
    int t = threadIdx.x & 127;
    int node = blockIdx.x * 2 + half;
    int c = t * 8;
    int k0 = offs[node], k1 = offs[node + 1];
    bf16x8 cv = *(const bf16x8*)(CB + (size_t)node * 2048 + c);
    float cf[8], a[8];
#pragma unroll
    for (int i = 0; i < 8; ++i) { cf[i] = (float)cv[i]; a[i] = 0.f; }
    for (int k = k0; k < k1; ++k) {
        int s = esrc[k];
        bf16x8 bv = *(const bf16x8*)(CB + (size_t)s * 2048 + 1024 + c);
#pragma unroll
        for (int i = 0; i < 8; ++i) a[i] += fmaxf(cf[i] + (float)bv[i], 0.f);
    }
    bf16x8 o;
#pragma unroll
    for (int i = 0; i < 8; ++i) o[i] = (bf16)a[i];
    *(bf16x8*)(Sb + (size_t)node * HID + c) = o;
}

// ---------------- stable head via MFMA ----------------
__global__ __launch_bounds__(64) void stable_mfma_kernel(const bf16* __restrict__ hb,
                                                         const bf16* __restrict__ swt,
                                                         const float* __restrict__ sb,
                                                         float* __restrict__ out) {
    int m0 = blockIdx.x * 16;  // NN = 625*16 exact
    int lane = threadIdx.x;
    int quad = lane >> 4, r15 = lane & 15;
    f32x4 acc0 = {}, acc1 = {};
    const bf16* arow = hb + (size_t)(m0 + r15) * HID + quad * 8;
    const bf16* b0 = swt + (size_t)r15 * HID + quad * 8;
    const bf16* b1p = swt + (size_t)(16 + r15) * HID + quad * 8;
    for (int k0 = 0; k0 < HID; k0 += 32) {
        bf16x8 af = *(const bf16x8*)(arow + k0);
        bf16x8 bf0 = *(const bf16x8*)(b0 + k0);
        bf16x8 bf1 = *(const bf16x8*)(b1p + k0);
        acc0 = __builtin_amdgcn_mfma_f32_16x16x32_bf16(af, bf0, acc0, 0, 0, 0);
        acc1 = __builtin_amdgcn_mfma_f32_16x16x32_bf16(af, bf1, acc1, 0, 0, 0);
    }
#pragma unroll
    for (int r = 0; r < 4; ++r) {
        int grow = m0 + quad * 4 + r;
        out[(size_t)grow * SDIM + r15] = acc0[r] + sb[r15];
        if (r15 < 2) out[(size_t)grow * SDIM + 16 + r15] = acc1[r] + sb[16 + r15];
    }
}

// ---------------- ghost head stage 2 ----------------
__global__ __launch_bounds__(256) void ghost_kernel(const float* __restrict__ g1,
                                                    const float* __restrict__ gw2,
                                                    const float* __restrict__ gb2,
                                                    float* __restrict__ out) {
    int w = threadIdx.x >> 6, lane = threadIdx.x & 63;
    int row = blockIdx.x * 4 + w;  // NN = 2500*4 exact
    const float4 gv = *(const float4*)(g1 + (size_t)row * GHID + lane * 4);
    const float4 wv = *(const float4*)(gw2 + lane * 4);
    float v = gv.x * wv.x + gv.y * wv.y + gv.z * wv.z + gv.w * wv.w;
#pragma unroll
    for (int o = 32; o > 0; o >>= 1) v += __shfl_down(v, o, 64);
    if (lane == 0) out[row] = 1.f / (1.f + expf(-(v + gb2[0])));
}

extern "C" void kernel_launch(void* const* d_in, const int* in_sizes, int n_in,
                              void* d_out, int out_size, void* d_ws, size_t ws_size,
                              hipStream_t stream) {
    const float* x   = (const float*)d_in[0];
    const int*   ei  = (const int*)d_in[1];
    const float* pw  = (const float*)d_in[2];
    const float* W1  = (const float*)d_in[3];
    const float* b1  = (const float*)d_in[4];
    const float* W2  = (const float*)d_in[5];
    const float* b2  = (const float*)d_in[6];
    const float* gw1 = (const float*)d_in[7];
    const float* gb1 = (const float*)d_in[8];
    const float* gw2 = (const float*)d_in[9];
    const float* gb2 = (const float*)d_in[10];
    const float* sw  = (const float*)d_in[11];
    const float* sb  = (const float*)d_in[12];

    float* out    = (float*)d_out;
    float* ghost  = out;                  // [N,1]
    float* stable = out + NN;             // [N,18]
    float* h      = out + NN + NN * SDIM; // [N,HID] fp32 (final h output)

    const size_t H2 = (size_t)HID * HID;
    float* ws   = (float*)d_ws;
    float* g1   = ws;                                  // NN*GHID fp32
    float* degF = g1 + (size_t)NN * GHID;              // NN
    float* cb   = degF + NN;                           // 4*2048 fp32
    bf16* hb    = (bf16*)(cb + 4 * 2048);              // NN*HID
    bf16* Sb    = hb + (size_t)NN * HID;               // NN*HID
    bf16* CB    = Sb + (size_t)NN * HID;               // NN*2048
    bf16* WT    = CB + (size_t)NN * 2048;              // 4 * 2*H2  ([Wd;Wb]^T per layer)
    bf16* W2t   = WT + 8 * H2;                         // 4*H2
    bf16* gw1t  = W2t + 4 * H2;                        // GHID*HID
    bf16* swt   = gw1t + (size_t)GHID * HID;           // 32*1024
    int*  cnt    = (int*)(swt + 32 * 1024);
    int*  offs   = cnt + NN;
    int*  cursor = offs + NN + 1;
    int*  esrc   = cursor + NN;

    // ---- fused prep (weights transpose/convert + swt + cb + cnt zero) ----
    prep_kernel<<<dim3(8648), 256, 0, stream>>>(W1, W2, gw1, sw, b1, WT, W2t, gw1t, swt, cb, cnt);

    // ---- CSR build ----
    count_kernel<<<dim3((EE + 255) / 256), 256, 0, stream>>>(ei, cnt);
    scan_kernel<<<dim3(1), 256, 0, stream>>>(cnt, offs, cursor, degF);
    scatter_kernel<<<dim3((EE + 255) / 256), 256, 0, stream>>>(ei, cursor, esrc);

    // ---- h0 ----
    proj_kernel<<<dim3(HID / 256, NN), 256, 0, stream>>>(x, pw, hb);

    dim3 gcbg(2048 / 128, (NN + 127) / 128);     // (16, 79) = 1264 blocks
    dim3 gw2grid(HID / 128, (NN + 127) / 128);   // (8, 79)  = 632 blocks
    for (int l = 0; l < NLAYERS; ++l) {
        // CB = hb @ [Wd ; Wb]^T + [b1 ; 0]   (N = 2048, fused Cn/Bn)
        mgemm3_kernel<0, 1, 0, 0, 1><<<gcbg, 256, 0, stream>>>(
            hb, WT + (size_t)l * 2 * H2, nullptr, CB, cb + l * 2048, nullptr, NN, 2048, HID);
        // S = segment_sum(relu(Cn[dst]+Bn[src]))
        gather_kernel<<<dim3(NN / 2), 256, 0, stream>>>(offs, esrc, CB, Sb);
        // h = relu(S @ W2 + deg*b2); last layer also writes fp32 h to d_out
        if (l < NLAYERS - 1)
            mgemm3_kernel<1, 1, 1, 0, 1><<<gw2grid, 256, 0, stream>>>(
                Sb, W2t + (size_t)l * H2, nullptr, hb, b2 + (size_t)l * HID, degF, NN, HID, HID);
        else
            mgemm3_kernel<1, 1, 1, 1, 1><<<gw2grid, 256, 0, stream>>>(
                Sb, W2t + (size_t)l * H2, h, hb, b2 + (size_t)l * HID, degF, NN, HID, HID);
    }

    // ---- ghost head (N=256, 158 blocks, single wave on new kernel) ----
    mgemm3_kernel<1, 1, 0, 1, 0><<<dim3(GHID / 128, (NN + 127) / 128), 256, 0, stream>>>(
        hb, gw1t, g1, nullptr, gb1, nullptr, NN, GHID, HID);
    ghost_kernel<<<dim3(NN / 4), 256, 0, stream>>>(g1, gw2, gb2, ghost);
    // ---- stable head (MFMA, 1 wave / 16 rows) ----
    stable_mfma_kernel<<<dim3(NN / 16), 64, 0, stream>>>(hb, swt, sb, stable);
}

// Round 8
// 710.472 us; speedup vs baseline: 1.1433x; 1.0080x over previous
//
#include <hip/hip_runtime.h>
#include <hip/hip_bf16.h>
#include <math.h>

#define NN 10000
#define EE 80000
#define SDIM 18
#define HID 1024
#define NLAYERS 4
#define GHID 256

typedef __bf16 bf16;
typedef __bf16 bf16x8 __attribute__((ext_vector_type(8)));
typedef __bf16 bf16x4 __attribute__((ext_vector_type(4)));
typedef float f32x4 __attribute__((ext_vector_type(4)));

#define AS1C(p) ((const __attribute__((address_space(1))) void*)(p))
#define AS3(p)  ((__attribute__((address_space(3))) void*)(p))

// ---------------- CSR build: count ----------------
__global__ void count_kernel(const int* __restrict__ ei, int* __restrict__ cnt) {
    int e = blockIdx.x * 256 + threadIdx.x;
    if (e < EE) atomicAdd(&cnt[ei[EE + e]], 1);
}

// ---------------- CSR build: exclusive scan (single block) ----------------
__global__ __launch_bounds__(256) void scan_kernel(const int* __restrict__ cnt,
                                                   int* __restrict__ offs,
                                                   int* __restrict__ cursor,
                                                   float* __restrict__ degF) {
    const int CH = 40;  // 256*40 = 10240 >= NN
    __shared__ int partial[256];
    int t = threadIdx.x;
    int base = t * CH;
    int local[CH];
    int sum = 0;
#pragma unroll
    for (int i = 0; i < CH; ++i) {
        int idx = base + i;
        int v = (idx < NN) ? cnt[idx] : 0;
        local[i] = sum;
        sum += v;
    }
    partial[t] = sum;
    __syncthreads();
    for (int off = 1; off < 256; off <<= 1) {
        int v = (t >= off) ? partial[t - off] : 0;
        __syncthreads();
        partial[t] += v;
        __syncthreads();
    }
    int excl = (t == 0) ? 0 : partial[t - 1];
#pragma unroll
    for (int i = 0; i < CH; ++i) {
        int idx = base + i;
        if (idx < NN) {
            int o = excl + local[i];
            offs[idx] = o;
            cursor[idx] = o;
            degF[idx] = (float)cnt[idx];
        }
    }
    if (t == 255) offs[NN] = partial[255];
}

// ---------------- CSR build: scatter edge sources ----------------
__global__ void scatter_kernel(const int* __restrict__ ei, int* __restrict__ cursor,
                               int* __restrict__ esrc) {
    int e = blockIdx.x * 256 + threadIdx.x;
    if (e < EE) {
        int dst = ei[EE + e];
        int pos = atomicAdd(&cursor[dst], 1);
        esrc[pos] = ei[e];
    }
}

// ---------------- fused prep: all weight transposes + swt + cb + cnt-zero ----------------
__global__ __launch_bounds__(256) void prep_kernel(const float* __restrict__ W1,
                                                   const float* __restrict__ W2,
                                                   const float* __restrict__ gw1,
                                                   const float* __restrict__ sw,
                                                   const float* __restrict__ b1,
                                                   bf16* __restrict__ WT,
                                                   bf16* __restrict__ W2t,
                                                   bf16* __restrict__ gw1t,
                                                   bf16* __restrict__ swt,
                                                   float* __restrict__ cb,
                                                   int* __restrict__ cnt) {
    __shared__ float td[32][33];
    __shared__ float tb[32][33];
    const size_t H2 = (size_t)HID * HID;
    int b = blockIdx.x;
    int tx = threadIdx.x & 31, ty = threadIdx.x >> 5;  // (32,8)

    if (b < 4096) {  // W1 fused diff transpose
        int l = b >> 10, r = b & 1023;
        int bx = (r & 31) * 32, by = (r >> 5) * 32;
        const float* s = W1 + (size_t)l * 2 * H2;
        bf16* d = WT + (size_t)l * 2 * H2;
#pragma unroll
        for (int r4 = 0; r4 < 4; ++r4) {
            int row = by + ty + r4 * 8;
            float vt = s[(size_t)row * HID + bx + tx];
            float vb = s[H2 + (size_t)row * HID + bx + tx];
            td[ty + r4 * 8][tx] = vt - vb;
            tb[ty + r4 * 8][tx] = vb;
        }
        __syncthreads();
#pragma unroll
        for (int r4 = 0; r4 < 4; ++r4) {
            int orow = bx + ty + r4 * 8;
            d[(size_t)orow * HID + by + tx] = (bf16)td[tx][ty + r4 * 8];
            d[(size_t)(HID + orow) * HID + by + tx] = (bf16)tb[tx][ty + r4 * 8];
        }
    } else if (b < 8192) {  // W2 transpose
        int sub = b - 4096;
        int l = sub >> 10, r = sub & 1023;
        int bx = (r & 31) * 32, by = (r >> 5) * 32;
        const float* s = W2 + (size_t)l * H2;
        bf16* d = W2t + (size_t)l * H2;
#pragma unroll
        for (int r4 = 0; r4 < 4; ++r4) {
            int row = by + ty + r4 * 8;
            td[ty + r4 * 8][tx] = s[(size_t)row * HID + bx + tx];
        }
        __syncthreads();
#pragma unroll
        for (int r4 = 0; r4 < 4; ++r4) {
            int orow = bx + ty + r4 * 8;
            d[(size_t)orow * HID + by + tx] = (bf16)td[tx][ty + r4 * 8];
        }
    } else if (b < 8448) {  // gw1 [1024][256] -> gw1t [256][1024]
        int sub = b - 8192;
        int bx = (sub & 7) * 32, by = (sub >> 3) * 32;
#pragma unroll
        for (int r4 = 0; r4 < 4; ++r4) {
            int row = by + ty + r4 * 8;
            td[ty + r4 * 8][tx] = gw1[(size_t)row * GHID + bx + tx];
        }
        __syncthreads();
#pragma unroll
        for (int r4 = 0; r4 < 4; ++r4) {
            int orow = bx + ty + r4 * 8;
            gw1t[(size_t)orow * HID + by + tx] = (bf16)td[tx][ty + r4 * 8];
        }
    } else if (b < 8576) {  // swt[32][1024] = sw[1024][18]^T zero-padded
        int i = (b - 8448) * 256 + threadIdx.x;
        int n = i >> 10, k = i & 1023;
        swt[i] = (bf16)(n < SDIM ? sw[k * SDIM + n] : 0.f);
    } else if (b < 8608) {  // cb[l][2048] = [b1[l] ; 0]
        int i = (b - 8576) * 256 + threadIdx.x;
        int l = i >> 11, c = i & 2047;
        cb[i] = (c < HID) ? b1[l * HID + c] : 0.f;
    } else {  // cnt zero
        int i = (b - 8608) * 256 + threadIdx.x;
        if (i < NN) cnt[i] = 0;
    }
}

// ---------------- h0 = sin(x@pw)*cos(x@pw) -> bf16 ----------------
__global__ __launch_bounds__(256) void proj_kernel(const float* __restrict__ x,
                                                   const float* __restrict__ pw,
                                                   bf16* __restrict__ hb) {
    int row = blockIdx.y;
    int col = blockIdx.x * 256 + threadIdx.x;
    __shared__ float xr[SDIM];
    if (threadIdx.x < SDIM) xr[threadIdx.x] = x[row * SDIM + threadIdx.x];
    __syncthreads();
    float acc = 0.f;
#pragma unroll
    for (int k = 0; k < SDIM; ++k) acc += xr[k] * pw[k * HID + col];
    hb[(size_t)row * HID + col] = (bf16)(sinf(acc) * cosf(acc));
}

// ---------------- 256x128 BK=32 triple-buffered counted-vmcnt MFMA GEMM ----------------
// R5-verified (58 us @ CB shape). 8 waves (4M x 2N, 64x64/wave), 512 threads.
// LDS 72 KiB -> 2 blocks/CU: B bufs [3][128*32] @ 0, A bufs [3][256*32] @ 12288.
// Per K-tile: {8 ds_read_b128 ; stage t+2 (3 gload_lds) ; lgkmcnt(0) ;
// setprio(1) ; 16 MFMA ; setprio(0) ; vmcnt(3) ; s_barrier}. vmcnt never 0
// in-loop (T4). Compile-time mod-3 buffers. T2 seg-XOR both-sides swizzle.
// GROUP-8 block swizzle. Used for CB (640 jobs: intensity-bound regime).
template <int RELU, int HAS_BIAS, int HAS_RS, int WF32, int WB16>
__global__ __launch_bounds__(512, 4) void mgemm3_kernel(const bf16* __restrict__ A,
                                                        const bf16* __restrict__ Bt,
                                                        float* __restrict__ C,
                                                        bf16* __restrict__ Cb,
                                                        const float* __restrict__ bias,
                                                        const float* __restrict__ rowscale,
                                                        int M, int N, int K) {
    __shared__ bf16 lds[36864];  // 72 KiB
    const int tid = threadIdx.x;
    const int wave = tid >> 6, lane = tid & 63;
    const int wm = wave >> 1, wn = wave & 1;  // 4M x 2N
    const int quad = lane >> 4, r15 = lane & 15;

    // ---- GROUP-8 block swizzle ----
    const int num_n = gridDim.x, num_m = gridDim.y;
    int bid = blockIdx.x + blockIdx.y * num_n;
    const int GROUP = 8;
    int width = GROUP * num_n;
    int group = bid / width;
    int rem = bid - group * width;
    int rows_ing = num_m - group * GROUP;
    rows_ing = rows_ing < GROUP ? rows_ing : GROUP;
    int by = group * GROUP + rem % rows_ing;
    int bx = rem / rows_ing;
    const int m0 = by * 256, n0 = bx * 128;

    // ---- staging: pre-swizzled global source, linear LDS dest ----
    const int strow = tid >> 2;  // 0..127
    const int segsw = ((tid & 3) ^ ((tid >> 3) & 3)) * 8;
    int ar0 = m0 + strow;        ar0 = ar0 < M ? ar0 : M - 1;
    int ar1 = m0 + 128 + strow;  ar1 = ar1 < M ? ar1 : M - 1;
    const bf16* ga0 = A + (size_t)ar0 * K + segsw;
    const bf16* ga1 = A + (size_t)ar1 * K + segsw;
    const bf16* gb  = Bt + (size_t)(n0 + strow) * K + segsw;
    const int ldst = (tid & ~63) * 8;  // wave-uniform elems; HW adds lane*16B

    // ---- ds_read per-lane offsets (elems, include swizzle) ----
    int aoff[4], boff[4];
#pragma unroll
    for (int i = 0; i < 4; ++i) {
        int rA = wm * 64 + i * 16 + r15;
        aoff[i] = 12288 + rA * 32 + (quad ^ ((rA >> 1) & 3)) * 8;
        int rB = wn * 64 + i * 16 + r15;
        boff[i] = rB * 32 + (quad ^ ((rB >> 1) & 3)) * 8;
    }

    f32x4 acc[4][4] = {};

#define STAGE3(bs, kt)                                                                                \
    do {                                                                                              \
        const int ko_ = (kt) << 5;                                                                    \
        __builtin_amdgcn_global_load_lds(AS1C(ga0 + ko_), AS3(&lds[12288 + (bs)*8192 + ldst]), 16, 0, 0); \
        __builtin_amdgcn_global_load_lds(AS1C(ga1 + ko_), AS3(&lds[12288 + (bs)*8192 + 4096 + ldst]), 16, 0, 0); \
        __builtin_amdgcn_global_load_lds(AS1C(gb + ko_), AS3(&lds[(bs)*4096 + ldst]), 16, 0, 0);      \
    } while (0)

    STAGE3(0, 0);
    STAGE3(1, 1);
    asm volatile("s_waitcnt vmcnt(3)");
    __builtin_amdgcn_s_barrier();

    const int NT = K >> 5;
    int t = 0;

#define TILE3(bi, bs)                                                                          \
    do {                                                                                       \
        int kt = (t + 2 < NT) ? (t + 2) : (t - 1);                                             \
        bf16x8 aF[4], bF[4];                                                                   \
        _Pragma("unroll") for (int i = 0; i < 4; ++i)                                          \
            aF[i] = *(const bf16x8*)(&lds[(bi)*8192 + aoff[i]]);                               \
        _Pragma("unroll") for (int j = 0; j < 4; ++j)                                          \
            bF[j] = *(const bf16x8*)(&lds[(bi)*4096 + boff[j]]);                               \
        STAGE3(bs, kt);                                                                        \
        asm volatile("s_waitcnt lgkmcnt(0)");                                                  \
        __builtin_amdgcn_s_setprio(1);                                                         \
        _Pragma("unroll") for (int i = 0; i < 4; ++i)                                          \
            _Pragma("unroll") for (int j = 0; j < 4; ++j)                                      \
                acc[i][j] = __builtin_amdgcn_mfma_f32_16x16x32_bf16(aF[i], bF[j], acc[i][j], 0, 0, 0); \
        __builtin_amdgcn_s_setprio(0);                                                         \
        asm volatile("s_waitcnt vmcnt(3)");                                                    \
        __builtin_amdgcn_s_barrier();                                                          \
        ++t;                                                                                   \
    } while (0)

    while (t + 3 <= NT) { TILE3(0, 2); TILE3(1, 0); TILE3(2, 1); }
    if (t < NT) TILE3(0, 2);
    if (t < NT) TILE3(1, 0);
#undef TILE3
#undef STAGE3

#pragma unroll
    for (int i = 0; i < 4; ++i) {
#pragma unroll
        for (int r = 0; r < 4; ++r) {
            int grow = m0 + wm * 64 + i * 16 + quad * 4 + r;
            if (grow >= M) continue;
            float rs = HAS_RS ? rowscale[grow] : 1.f;
#pragma unroll
            for (int j = 0; j < 4; ++j) {
                int gcol = n0 + wn * 64 + j * 16 + r15;
                float v = acc[i][j][r];
                if (HAS_BIAS) v += rs * bias[gcol];
                if (RELU) v = fmaxf(v, 0.f);
                if (WF32) C[(size_t)grow * N + gcol] = v;
                if (WB16) Cb[(size_t)grow * N + gcol] = (bf16)v;
            }
        }
    }
}

// ---------------- 128x128 BK=32 triple-buffered counted-vmcnt MFMA GEMM ----------------
// R7-verified. 4 waves (2M x 2N), 256 threads, LDS 48 KiB -> 3 blocks/CU.
// Same schedule invariants as mgemm3. Used for W2 (632 jobs) and ghost (158):
// sub-single-wave regime where occupancy beats intensity (R7: W2 -8 us/layer).
template <int RELU, int HAS_BIAS, int HAS_RS, int WF32, int WB16>
__global__ __launch_bounds__(256, 3) void mgemm3h_kernel(const bf16* __restrict__ A,
                                                         const bf16* __restrict__ Bt,
                                                         float* __restrict__ C,
                                                         bf16* __restrict__ Cb,
                                                         const float* __restrict__ bias,
                                                         const float* __restrict__ rowscale,
                                                         int M, int N, int K) {
    __shared__ bf16 lds[24576];  // 48 KiB
    const int tid = threadIdx.x;
    const int wave = tid >> 6, lane = tid & 63;
    const int wm = wave >> 1, wn = wave & 1;  // 2M x 2N
    const int quad = lane >> 4, r15 = lane & 15;

    // ---- GROUP-8 block swizzle ----
    const int num_n = gridDim.x, num_m = gridDim.y;
    int bid = blockIdx.x + blockIdx.y * num_n;
    const int GROUP = 8;
    int width = GROUP * num_n;
    int group = bid / width;
    int rem = bid - group * width;
    int rows_ing = num_m - group * GROUP;
    rows_ing = rows_ing < GROUP ? rows_ing : GROUP;
    int by = group * GROUP + rem % rows_ing;
    int bx = rem / rows_ing;
    const int m0 = by * 128, n0 = bx * 128;

    // ---- staging: pre-swizzled global source, linear LDS dest ----
    const int strow = tid >> 2;  // 0..63
    const int segsw = ((tid & 3) ^ ((tid >> 3) & 3)) * 8;
    int ar0 = m0 + strow;       ar0 = ar0 < M ? ar0 : M - 1;
    int ar1 = m0 + 64 + strow;  ar1 = ar1 < M ? ar1 : M - 1;
    const bf16* ga0 = A + (size_t)ar0 * K + segsw;
    const bf16* ga1 = A + (size_t)ar1 * K + segsw;
    const bf16* gb0 = Bt + (size_t)(n0 + strow) * K + segsw;
    const bf16* gb1 = Bt + (size_t)(n0 + 64 + strow) * K + segsw;
    const int ldst = (tid & ~63) * 8;

    int aoff[4], boff[4];
#pragma unroll
    for (int i = 0; i < 4; ++i) {
        int rA = wm * 64 + i * 16 + r15;
        aoff[i] = 12288 + rA * 32 + (quad ^ ((rA >> 1) & 3)) * 8;
        int rB = wn * 64 + i * 16 + r15;
        boff[i] = rB * 32 + (quad ^ ((rB >> 1) & 3)) * 8;
    }

    f32x4 acc[4][4] = {};

#define STAGE3H(bs, kt)                                                                                  \
    do {                                                                                                 \
        const int ko_ = (kt) << 5;                                                                       \
        __builtin_amdgcn_global_load_lds(AS1C(ga0 + ko_), AS3(&lds[12288 + (bs)*4096 + ldst]), 16, 0, 0); \
        __builtin_amdgcn_global_load_lds(AS1C(ga1 + ko_), AS3(&lds[12288 + (bs)*4096 + 2048 + ldst]), 16, 0, 0); \
        __builtin_amdgcn_global_load_lds(AS1C(gb0 + ko_), AS3(&lds[(bs)*4096 + ldst]), 16, 0, 0);        \
        __builtin_amdgcn_global_load_lds(AS1C(gb1 + ko_), AS3(&lds[(bs)*4096 + 2048 + ldst]), 16, 0, 0); \
    } while (0)

    STAGE3H(0, 0);
    STAGE3H(1, 1);
    asm volatile("s_waitcnt vmcnt(4)");
    __builtin_amdgcn_s_barrier();

    const int NT = K >> 5;
    int t = 0;

#define TILE3H(bi, bs)                                                                         \
    do {                                                                                       \
        int kt = (t + 2 < NT) ? (t + 2) : (t - 1);                                             \
        bf16x8 aF[4], bF[4];                                                                   \
        _Pragma("unroll") for (int i = 0; i < 4; ++i)                                          \
            aF[i] = *(const bf16x8*)(&lds[(bi)*4096 + aoff[i]]);                               \
        _Pragma("unroll") for (int j = 0; j < 4; ++j)                                          \
            bF[j] = *(const bf16x8*)(&lds[(bi)*4096 + boff[j]]);                               \
        STAGE3H(bs, kt);                                                                       \
        asm volatile("s_waitcnt lgkmcnt(0)");                                                  \
        __builtin_amdgcn_s_setprio(1);                                                         \
        _Pragma("unroll") for (int i = 0; i < 4; ++i)                                          \
            _Pragma("unroll") for (int j = 0; j < 4; ++j)                                      \
                acc[i][j] = __builtin_amdgcn_mfma_f32_16x16x32_bf16(aF[i], bF[j], acc[i][j], 0, 0, 0); \
        __builtin_amdgcn_s_setprio(0);                                                         \
        asm volatile("s_waitcnt vmcnt(4)");                                                    \
        __builtin_amdgcn_s_barrier();                                                          \
        ++t;                                                                                   \
    } while (0)

    while (t + 3 <= NT) { TILE3H(0, 2); TILE3H(1, 0); TILE3H(2, 1); }
    if (t < NT) TILE3H(0, 2);
    if (t < NT) TILE3H(1, 0);
#undef TILE3H
#undef STAGE3H

#pragma unroll
    for (int i = 0; i < 4; ++i) {
#pragma unroll
        for (int r = 0; r < 4; ++r) {
            int grow = m0 + wm * 64 + i * 16 + quad * 4 + r;
            if (grow >= M) continue;
            float rs = HAS_RS ? rowscale[grow] : 1.f;
#pragma unroll
            for (int j = 0; j < 4; ++j) {
                int gcol = n0 + wn * 64 + j * 16 + r15;
                float v = acc[i][j][r];
                if (HAS_BIAS) v += rs * bias[gcol];
                if (RELU) v = fmaxf(v, 0.f);
                if (WF32) C[(size_t)grow * N + gcol] = v;
                if (WB16) Cb[(size_t)grow * N + gcol] = (bf16)v;
            }
        }
    }
}

// ---------------- CSR aggregation over CB[node][2048] = [Cn ; Bn] ----------------
__global__ __launch_bounds__(256) void gather_kernel(const int* __restrict__ offs,
                                                     const int* __restrict__ esrc,
                                                     const bf16* __restrict__ CB,
                                                     bf16* __restrict__ Sb) {
    int half = threadIdx.x >> 7;
    int t = threadIdx.x & 127;
    int node = blockIdx.x * 2 + half;
    int c = t * 8;
    int k0 = offs[node], k1 = offs[node + 1];
    bf16x8 cv = *(const bf16x8*)(CB + (size_t)node * 2048 + c);
    float cf[8], a[8];
#pragma unroll
    for (int i = 0; i < 8; ++i) { cf[i] = (float)cv[i]; a[i] = 0.f; }
    for (int k = k0; k < k1; ++k) {
        int s = esrc[k];
        bf16x8 bv = *(const bf16x8*)(CB + (size_t)s * 2048 + 1024 + c);
#pragma unroll
        for (int i = 0; i < 8; ++i) a[i] += fmaxf(cf[i] + (float)bv[i], 0.f);
    }
    bf16x8 o;
#pragma unroll
    for (int i = 0; i < 8; ++i) o[i] = (bf16)a[i];
    *(bf16x8*)(Sb + (size_t)node * HID + c) = o;
}

// ---------------- stable head via MFMA ----------------
__global__ __launch_bounds__(64) void stable_mfma_kernel(const bf16* __restrict__ hb,
                                                         const bf16* __restrict__ swt,
                                                         const float* __restrict__ sb,
                                                         float* __restrict__ out) {
    int m0 = blockIdx.x * 16;  // NN = 625*16 exact
    int lane = threadIdx.x;
    int quad = lane >> 4, r15 = lane & 15;
    f32x4 acc0 = {}, acc1 = {};
    const bf16* arow = hb + (size_t)(m0 + r15) * HID + quad * 8;
    const bf16* b0 = swt + (size_t)r15 * HID + quad * 8;
    const bf16* b1p = swt + (size_t)(16 + r15) * HID + quad * 8;
    for (int k0 = 0; k0 < HID; k0 += 32) {
        bf16x8 af = *(const bf16x8*)(arow + k0);
        bf16x8 bf0 = *(const bf16x8*)(b0 + k0);
        bf16x8 bf1 = *(const bf16x8*)(b1p + k0);
        acc0 = __builtin_amdgcn_mfma_f32_16x16x32_bf16(af, bf0, acc0, 0, 0, 0);
        acc1 = __builtin_amdgcn_mfma_f32_16x16x32_bf16(af, bf1, acc1, 0, 0, 0);
    }
#pragma unroll
    for (int r = 0; r < 4; ++r) {
        int grow = m0 + quad * 4 + r;
        out[(size_t)grow * SDIM + r15] = acc0[r] + sb[r15];
        if (r15 < 2) out[(size_t)grow * SDIM + 16 + r15] = acc1[r] + sb[16 + r15];
    }
}

// ---------------- ghost head stage 2 ----------------
__global__ __launch_bounds__(256) void ghost_kernel(const float* __restrict__ g1,
                                                    const float* __restrict__ gw2,
                                                    const float* __restrict__ gb2,
                                                    float* __restrict__ out) {
    int w = threadIdx.x >> 6, lane = threadIdx.x & 63;
    int row = blockIdx.x * 4 + w;  // NN = 2500*4 exact
    const float4 gv = *(const float4*)(g1 + (size_t)row * GHID + lane * 4);
    const float4 wv = *(const float4*)(gw2 + lane * 4);
    float v = gv.x * wv.x + gv.y * wv.y + gv.z * wv.z + gv.w * wv.w;
#pragma unroll
    for (int o = 32; o > 0; o >>= 1) v += __shfl_down(v, o, 64);
    if (lane == 0) out[row] = 1.f / (1.f + expf(-(v + gb2[0])));
}

extern "C" void kernel_launch(void* const* d_in, const int* in_sizes, int n_in,
                              void* d_out, int out_size, void* d_ws, size_t ws_size,
                              hipStream_t stream) {
    const float* x   = (const float*)d_in[0];
    const int*   ei  = (const int*)d_in[1];
    const float* pw  = (const float*)d_in[2];
    const float* W1  = (const float*)d_in[3];
    const float* b1  = (const float*)d_in[4];
    const float* W2  = (const float*)d_in[5];
    const float* b2  = (const float*)d_in[6];
    const float* gw1 = (const float*)d_in[7];
    const float* gb1 = (const float*)d_in[8];
    const float* gw2 = (const float*)d_in[9];
    const float* gb2 = (const float*)d_in[10];
    const float* sw  = (const float*)d_in[11];
    const float* sb  = (const float*)d_in[12];

    float* out    = (float*)d_out;
    float* ghost  = out;                  // [N,1]
    float* stable = out + NN;             // [N,18]
    float* h      = out + NN + NN * SDIM; // [N,HID] fp32 (final h output)

    const size_t H2 = (size_t)HID * HID;
    float* ws   = (float*)d_ws;
    float* g1   = ws;                                  // NN*GHID fp32
    float* degF = g1 + (size_t)NN * GHID;              // NN
    float* cb   = degF + NN;                           // 4*2048 fp32
    bf16* hb    = (bf16*)(cb + 4 * 2048);              // NN*HID
    bf16* Sb    = hb + (size_t)NN * HID;               // NN*HID
    bf16* CB    = Sb + (size_t)NN * HID;               // NN*2048
    bf16* WT    = CB + (size_t)NN * 2048;              // 4 * 2*H2  ([Wd;Wb]^T per layer)
    bf16* W2t   = WT + 8 * H2;                         // 4*H2
    bf16* gw1t  = W2t + 4 * H2;                        // GHID*HID
    bf16* swt   = gw1t + (size_t)GHID * HID;           // 32*1024
    int*  cnt    = (int*)(swt + 32 * 1024);
    int*  offs   = cnt + NN;
    int*  cursor = offs + NN + 1;
    int*  esrc   = cursor + NN;

    // ---- fused prep (weights transpose/convert + swt + cb + cnt zero) ----
    prep_kernel<<<dim3(8648), 256, 0, stream>>>(W1, W2, gw1, sw, b1, WT, W2t, gw1t, swt, cb, cnt);

    // ---- CSR build ----
    count_kernel<<<dim3((EE + 255) / 256), 256, 0, stream>>>(ei, cnt);
    scan_kernel<<<dim3(1), 256, 0, stream>>>(cnt, offs, cursor, degF);
    scatter_kernel<<<dim3((EE + 255) / 256), 256, 0, stream>>>(ei, cursor, esrc);

    // ---- h0 ----
    proj_kernel<<<dim3(HID / 256, NN), 256, 0, stream>>>(x, pw, hb);

    dim3 gcbg(2048 / 128, (NN + 255) / 256);     // (16, 40) = 640 blocks @ 256x128
    dim3 gw2grid(HID / 128, (NN + 127) / 128);   // (8, 79)  = 632 blocks @ 128x128
    for (int l = 0; l < NLAYERS; ++l) {
        // CB = hb @ [Wd ; Wb]^T + [b1 ; 0]   (N = 2048, fused Cn/Bn)
        mgemm3_kernel<0, 1, 0, 0, 1><<<gcbg, 512, 0, stream>>>(
            hb, WT + (size_t)l * 2 * H2, nullptr, CB, cb + l * 2048, nullptr, NN, 2048, HID);
        // S = segment_sum(relu(Cn[dst]+Bn[src]))
        gather_kernel<<<dim3(NN / 2), 256, 0, stream>>>(offs, esrc, CB, Sb);
        // h = relu(S @ W2 + deg*b2); last layer also writes fp32 h to d_out
        if (l < NLAYERS - 1)
            mgemm3h_kernel<1, 1, 1, 0, 1><<<gw2grid, 256, 0, stream>>>(
                Sb, W2t + (size_t)l * H2, nullptr, hb, b2 + (size_t)l * HID, degF, NN, HID, HID);
        else
            mgemm3h_kernel<1, 1, 1, 1, 1><<<gw2grid, 256, 0, stream>>>(
                Sb, W2t + (size_t)l * H2, h, hb, b2 + (size_t)l * HID, degF, NN, HID, HID);
    }

    // ---- ghost head (N=256, 158 blocks @ 128x128) ----
    mgemm3h_kernel<1, 1, 0, 1, 0><<<dim3(GHID / 128, (NN + 127) / 128), 256, 0, stream>>>(
        hb, gw1t, g1, nullptr, gb1, nullptr, NN, GHID, HID);
    ghost_kernel<<<dim3(NN / 4), 256, 0, stream>>>(g1, gw2, gb2, ghost);
    // ---- stable head (MFMA, 1 wave / 16 rows) ----
    stable_mfma_kernel<<<dim3(NN / 16), 64, 0, stream>>>(hb, swt, sb, stable);
}